// Round 2
// baseline (1059.018 us; speedup 1.0000x reference)
//
#include <hip/hip_runtime.h>
#include <stdint.h>
#include <stddef.h>

// Problem constants
constexpr int NB = 4;      // batch
constexpr int NC = 256;    // channels
constexpr int HW = 64;     // spatial side
constexpr int NP = 4096;   // HW*HW
constexpr int NM = 8;      // matrices for Newton-Schulz: 2 feats x 4 batches
constexpr int NS_ITERS = 7;       // lam_scaled ~0.135 -> residual saturates fp32 eps at 7
constexpr int NSLAB = 128;        // score slabs (combine fused via atomicMax)
constexpr int PSLAB = NP / NSLAB; // 32
constexpr int KSPLIT = 8;         // cov K-split
constexpr int KCHUNK = NP / KSPLIT; // 512
constexpr int NTILE8 = 36;        // upper-tri 32-tiles in 8x8 grid (NS symmetric)

// fp16 Markidis split (bf16 2-split caused argmax flips). Pre-scale by 512
// keeps lo out of fp16-subnormal range; uniform scaling is argmax-invariant
// for D, and is divided back out for cov.
constexpr float SPLIT_SCALE = 512.0f;
constexpr double COV_DESCALE = 1.0 / ((double)SPLIT_SCALE * (double)SPLIT_SCALE);

typedef __attribute__((ext_vector_type(8))) _Float16 h8v;  // 8 fp16 (4 VGPRs)
typedef __attribute__((ext_vector_type(4))) _Float16 h4v;  // 4 fp16 (8B store)
typedef __attribute__((ext_vector_type(4))) float f4v;     // MFMA acc

// async global->LDS, 16B per lane; lds arg must be wave-uniform
#define GLD16(lds, g)                                                        \
  __builtin_amdgcn_global_load_lds(                                          \
      (const __attribute__((address_space(1))) void*)(g),                    \
      (__attribute__((address_space(3))) void*)(lds), 16, 0, 0)

// monotone float -> sortable u32 (finite inputs): order(f) == order(sortable(f))
__device__ inline unsigned sortable_f32(float f) {
  unsigned u = __float_as_uint(f);
  return (u & 0x80000000u) ? ~u : (u | 0x80000000u);
}

// ---------------------------------------------------------------------------
// 1. fused mean + raw fp16 split: (src-mu)*512 -> fp16 hi/lo in [c][p]
__global__ __launch_bounds__(256) void meansplit_kernel(const float* __restrict__ content,
                                                        const float* __restrict__ style,
                                                        float* __restrict__ mean,
                                                        _Float16* __restrict__ Czh,
                                                        _Float16* __restrict__ Czl) {
  int id = blockIdx.x;              // [0, 2*NB*NC) == m*NC + c
  int feat = id / (NB * NC);
  int bc = id % (NB * NC);
  const float* src = (feat ? style : content) + (size_t)bc * NP;
  int tid = threadIdx.x;
  float s = 0.f;
  for (int i = tid; i < NP; i += 256) s += src[i];
  __shared__ float red[256];
  red[tid] = s;
  __syncthreads();
  for (int st = 128; st > 0; st >>= 1) {
    if (tid < st) red[tid] += red[tid + st];
    __syncthreads();
  }
  float mu = red[0] * (1.0f / NP);
  if (tid == 0) mean[id] = mu;
  _Float16* oh = Czh + (size_t)id * NP;
  _Float16* ol = Czl + (size_t)id * NP;
  for (int f4 = tid; f4 < NP / 4; f4 += 256) {
    float4 v = *(const float4*)&src[f4 * 4];
    float vv[4] = {v.x, v.y, v.z, v.w};
    h4v h, l;
#pragma unroll
    for (int q = 0; q < 4; q++) {
      float sv = (vv[q] - mu) * SPLIT_SCALE;
      _Float16 hh = (_Float16)sv;
      h[q] = hh;
      l[q] = (_Float16)(sv - (float)hh);
    }
    *(h4v*)&oh[f4 * 4] = h;
    *(h4v*)&ol[f4 * 4] = l;
  }
}

// ---------------------------------------------------------------------------
// 2. MFMA syrk cov: 64x64 upper-tri tiles, 4-term fp16 split, per-32-k fp64 fold
__global__ __launch_bounds__(256) void cov_mfma_kernel(const _Float16* __restrict__ Czh,
                                                       const _Float16* __restrict__ Czl,
                                                       double* __restrict__ pcov) {
  __shared__ _Float16 sAh[64 * 32], sAl[64 * 32], sBh[64 * 32], sBl[64 * 32];
  int m = blockIdx.z;
  int t = blockIdx.x, ti = 0, rem = t;
  while (rem >= 4 - ti) { rem -= 4 - ti; ti++; }
  int tj = ti + rem;
  int i0 = ti * 64, j0 = tj * 64;
  const _Float16* Ah = Czh + ((size_t)m * NC + i0) * NP;
  const _Float16* Al = Czl + ((size_t)m * NC + i0) * NP;
  const _Float16* Bh = Czh + ((size_t)m * NC + j0) * NP;
  const _Float16* Bl = Czl + ((size_t)m * NC + j0) * NP;
  int k0base = blockIdx.y * KCHUNK;
  int tid = threadIdx.x, lane = tid & 63;
  int mm = lane & 15, quad = lane >> 4;
  int w = tid >> 6, qr = w & 1, qc = w >> 1;
  double dacc[2][2][4] = {};
  for (int step = 0; step < KCHUNK / 32; step++) {
    int k0 = k0base + step * 32;
    __syncthreads();
    {
      int row = tid >> 2, koff = (tid & 3) * 8;
      int sbase = (tid & ~63) * 8;   // wave-uniform
      GLD16(&sAh[sbase], Ah + (size_t)row * NP + k0 + koff);
      GLD16(&sAl[sbase], Al + (size_t)row * NP + k0 + koff);
      GLD16(&sBh[sbase], Bh + (size_t)row * NP + k0 + koff);
      GLD16(&sBl[sbase], Bl + (size_t)row * NP + k0 + koff);
    }
    __syncthreads();   // drains vmcnt per barrier semantics
    h8v afh[2], afl[2], bfh[2], bfl[2];
#pragma unroll
    for (int tt = 0; tt < 2; tt++) {
      int ra = (qr * 32 + tt * 16 + mm) * 32 + quad * 8;
      afh[tt] = *(const h8v*)&sAh[ra];
      afl[tt] = *(const h8v*)&sAl[ra];
      int rb = (qc * 32 + tt * 16 + mm) * 32 + quad * 8;
      bfh[tt] = *(const h8v*)&sBh[rb];
      bfl[tt] = *(const h8v*)&sBl[rb];
    }
    f4v acc[2][2] = {};
#pragma unroll
    for (int tr = 0; tr < 2; tr++)
#pragma unroll
      for (int tc = 0; tc < 2; tc++) {
        acc[tr][tc] = __builtin_amdgcn_mfma_f32_16x16x32_f16(afh[tr], bfh[tc], acc[tr][tc], 0, 0, 0);
        acc[tr][tc] = __builtin_amdgcn_mfma_f32_16x16x32_f16(afh[tr], bfl[tc], acc[tr][tc], 0, 0, 0);
        acc[tr][tc] = __builtin_amdgcn_mfma_f32_16x16x32_f16(afl[tr], bfh[tc], acc[tr][tc], 0, 0, 0);
        acc[tr][tc] = __builtin_amdgcn_mfma_f32_16x16x32_f16(afl[tr], bfl[tc], acc[tr][tc], 0, 0, 0);
      }
#pragma unroll
    for (int tr = 0; tr < 2; tr++)
#pragma unroll
      for (int tc = 0; tc < 2; tc++)
#pragma unroll
        for (int r = 0; r < 4; r++) dacc[tr][tc][r] += (double)acc[tr][tc][r];
  }
  double* dst = pcov + ((size_t)blockIdx.y * NM + m) * NC * NC;
  // C/D layout: col = lane&15, row = quad*4 + reg  [verified mapping]
#pragma unroll
  for (int tr = 0; tr < 2; tr++)
#pragma unroll
    for (int tc = 0; tc < 2; tc++)
#pragma unroll
      for (int r = 0; r < 4; r++) {
        int row = i0 + qr * 32 + tr * 16 + quad * 4 + r;
        int col = j0 + qc * 32 + tc * 16 + mm;
        dst[(size_t)row * NC + col] = dacc[tr][tc][r];
      }
}

// 2b. sum K-split partials; mirror lower triangle from upper tiles; descale
__global__ __launch_bounds__(256) void cov_reduce_kernel(const double* __restrict__ pcov,
                                                         double* __restrict__ cov) {
  size_t idx = (size_t)blockIdx.x * 256 + threadIdx.x;  // [0, NM*NC*NC)
  int m = (int)(idx >> 16);
  int ij = (int)(idx & 65535);
  int i = ij >> 8, j = ij & 255;
  int src = ((i >> 6) <= (j >> 6)) ? ij : ((j << 8) | i);
  double s = 0;
  for (int k = 0; k < KSPLIT; k++)
    s += pcov[((size_t)k * NM + m) * 65536 + src];
  cov[idx] = s * COV_DESCALE;
}

// ---------------------------------------------------------------------------
// 2c. fp16 tile transpose: Czh/Czl [m][k][p] -> CzhT/CzlT [m][p][k], so the
//     MFMA whiten can read k-contiguous A fragments. 64x64 tiles, LDS pad 72
//     (144B stride: 8B-aligned, 2-way bank alias = free).
__global__ __launch_bounds__(256) void transpose_kernel(const _Float16* __restrict__ Czh,
                                                        const _Float16* __restrict__ Czl,
                                                        _Float16* __restrict__ CzhT,
                                                        _Float16* __restrict__ CzlT) {
  __shared__ unsigned short th[64][72], tl[64][72];
  int m = blockIdx.z;
  int p0 = blockIdx.x * 64, k0 = blockIdx.y * 64;
  int tid = threadIdx.x;
  const unsigned short* src_h = (const unsigned short*)(Czh + (size_t)m * NC * NP);
  const unsigned short* src_l = (const unsigned short*)(Czl + (size_t)m * NC * NP);
#pragma unroll
  for (int j = 0; j < 4; j++) {
    int e = j * 1024 + tid * 4;
    int kk = e >> 6, pp = e & 63;
    ushort4 vh = *(const ushort4*)&src_h[(size_t)(k0 + kk) * NP + p0 + pp];
    ushort4 vl = *(const ushort4*)&src_l[(size_t)(k0 + kk) * NP + p0 + pp];
    *(ushort4*)&th[kk][pp] = vh;
    *(ushort4*)&tl[kk][pp] = vl;
  }
  __syncthreads();
  unsigned short* dst_h = (unsigned short*)(CzhT + (size_t)m * NP * NC);
  unsigned short* dst_l = (unsigned short*)(CzlT + (size_t)m * NP * NC);
#pragma unroll
  for (int j = 0; j < 4; j++) {
    int e = j * 1024 + tid * 4;
    int pp = e >> 6, kk = e & 63;
    ushort4 vh, vl;
    vh.x = th[kk][pp];     vh.y = th[kk + 1][pp];
    vh.z = th[kk + 2][pp]; vh.w = th[kk + 3][pp];
    vl.x = tl[kk][pp];     vl.y = tl[kk + 1][pp];
    vl.z = tl[kk + 2][pp]; vl.w = tl[kk + 3][pp];
    *(ushort4*)&dst_h[(size_t)(p0 + pp) * NC + k0 + kk] = vh;
    *(ushort4*)&dst_l[(size_t)(p0 + pp) * NC + k0 + kk] = vl;
  }
}

// ---------------------------------------------------------------------------
// 3. Gershgorin bound; init Y = s*A, Z = I. Y/Z fp32 (coupled NS is stable,
//    err ~ cond*eps_f32 ~ 2e-7 rel). scaleArr stays fp64.
__global__ __launch_bounds__(256) void bound_init_kernel(const double* __restrict__ cov,
                                                         float* __restrict__ Y,
                                                         float* __restrict__ Z,
                                                         double* __restrict__ scaleArr) {
  int m = blockIdx.x;
  const double* A = cov + (size_t)m * NC * NC;
  int t = threadIdx.x;
  double s = 0;
  for (int i = 0; i < NC; i++) s += fabs(A[(size_t)i * NC + t]);   // coalesced
  __shared__ double red[256];
  red[t] = s;
  __syncthreads();
  for (int st = 128; st > 0; st >>= 1) {
    if (t < st) red[t] = fmax(red[t], red[t + st]);
    __syncthreads();
  }
  double scale = 1.0 / red[0];     // lam_max <= max abs row sum (rigorous upper bound)
  if (t == 0) scaleArr[m] = scale;
  float* Ym = Y + (size_t)m * NC * NC;
  float* Zm = Z + (size_t)m * NC * NC;
  for (int idx = t; idx < NC * NC; idx += 256) {
    Ym[idx] = (float)(A[idx] * scale);
    Zm[idx] = ((idx / NC) == (idx % NC)) ? 1.0f : 0.0f;
  }
}

// ---------------------------------------------------------------------------
// NS iterates are polynomials in symmetric A -> Y, Z, T, Y*T, T*Z all
// symmetric. Upper-tri 32x32 tiles only, mirror-write lower. fp32.

// 4a. T = Z * Y (fp32, upper-tri 32x32 tiles, 2x2 micro, mirrored writes)
__global__ __launch_bounds__(256) void ns_t_kernel(const float* __restrict__ Zin,
                                                   const float* __restrict__ Yin,
                                                   float* __restrict__ T) {
  int m = blockIdx.z;
  const float* Am = Zin + (size_t)m * NC * NC;
  const float* Bm = Yin + (size_t)m * NC * NC;
  float* Tm = T + (size_t)m * NC * NC;
  __shared__ float As[32][33];
  __shared__ float Bs[32][33];
  int tid = threadIdx.x, tx = tid & 15, ty = tid >> 4;
  int t = blockIdx.x, ti = 0, rem = t;     // unrank upper-tri tile (8x8 grid)
  while (rem >= 8 - ti) { rem -= 8 - ti; ti++; }
  int tj = ti + rem;
  int i0 = ti * 32, j0 = tj * 32;
  float a00 = 0, a01 = 0, a10 = 0, a11 = 0;
  for (int k0 = 0; k0 < NC; k0 += 32) {
    for (int idx = tid; idx < 1024; idx += 256) {
      int r = idx >> 5, cc = idx & 31;
      As[r][cc] = Am[(size_t)(i0 + r) * NC + k0 + cc];
      Bs[r][cc] = Bm[(size_t)(k0 + r) * NC + j0 + cc];
    }
    __syncthreads();
#pragma unroll
    for (int kk = 0; kk < 32; kk++) {
      float x0 = As[ty * 2][kk], x1 = As[ty * 2 + 1][kk];
      float y0 = Bs[kk][tx * 2], y1 = Bs[kk][tx * 2 + 1];
      a00 += x0 * y0; a01 += x0 * y1; a10 += x1 * y0; a11 += x1 * y1;
    }
    __syncthreads();
  }
  Tm[(size_t)(i0 + ty * 2) * NC + j0 + tx * 2] = a00;
  Tm[(size_t)(i0 + ty * 2) * NC + j0 + tx * 2 + 1] = a01;
  Tm[(size_t)(i0 + ty * 2 + 1) * NC + j0 + tx * 2] = a10;
  Tm[(size_t)(i0 + ty * 2 + 1) * NC + j0 + tx * 2 + 1] = a11;
  if (ti != tj) {   // mirror tile, coalesced via LDS transpose (reuse As)
    As[ty * 2][tx * 2] = a00;
    As[ty * 2][tx * 2 + 1] = a01;
    As[ty * 2 + 1][tx * 2] = a10;
    As[ty * 2 + 1][tx * 2 + 1] = a11;
    __syncthreads();
    for (int idx = tid; idx < 1024; idx += 256) {
      int r = idx >> 5, cc = idx & 31;
      Tm[(size_t)(j0 + r) * NC + i0 + cc] = As[cc][r];
    }
  }
}

// 4b. Yout = 1.5*Yin - 0.5*Yin*T ; Zout = 1.5*Zin - 0.5*T*Zin  (fp32)
__global__ __launch_bounds__(256) void ns_upd_kernel(const float* __restrict__ Yin,
                                                     const float* __restrict__ Zin,
                                                     const float* __restrict__ T,
                                                     float* __restrict__ Yout,
                                                     float* __restrict__ Zout) {
  int z = blockIdx.z;
  int m = z & 7, which = z >> 3;
  size_t off = (size_t)m * NC * NC;
  const float* Am = which == 0 ? (Yin + off) : (T + off);
  const float* Bm = which == 0 ? (T + off) : (Zin + off);
  const float* Sm = which == 0 ? (Yin + off) : (Zin + off);
  float* Om = which == 0 ? (Yout + off) : (Zout + off);
  __shared__ float As[32][33];
  __shared__ float Bs[32][33];
  int tid = threadIdx.x, tx = tid & 15, ty = tid >> 4;
  int t = blockIdx.x, ti = 0, rem = t;     // unrank upper-tri tile (8x8 grid)
  while (rem >= 8 - ti) { rem -= 8 - ti; ti++; }
  int tj = ti + rem;
  int i0 = ti * 32, j0 = tj * 32;
  float a00 = 0, a01 = 0, a10 = 0, a11 = 0;
  for (int k0 = 0; k0 < NC; k0 += 32) {
    for (int idx = tid; idx < 1024; idx += 256) {
      int r = idx >> 5, cc = idx & 31;
      As[r][cc] = Am[(size_t)(i0 + r) * NC + k0 + cc];
      Bs[r][cc] = Bm[(size_t)(k0 + r) * NC + j0 + cc];
    }
    __syncthreads();
#pragma unroll
    for (int kk = 0; kk < 32; kk++) {
      float x0 = As[ty * 2][kk], x1 = As[ty * 2 + 1][kk];
      float y0 = Bs[kk][tx * 2], y1 = Bs[kk][tx * 2 + 1];
      a00 += x0 * y0; a01 += x0 * y1; a10 += x1 * y0; a11 += x1 * y1;
    }
    __syncthreads();
  }
  int r0 = i0 + ty * 2, c0 = j0 + tx * 2;
  float o00 = 1.5f * Sm[(size_t)r0 * NC + c0] - 0.5f * a00;
  float o01 = 1.5f * Sm[(size_t)r0 * NC + c0 + 1] - 0.5f * a01;
  float o10 = 1.5f * Sm[(size_t)(r0 + 1) * NC + c0] - 0.5f * a10;
  float o11 = 1.5f * Sm[(size_t)(r0 + 1) * NC + c0 + 1] - 0.5f * a11;
  Om[(size_t)r0 * NC + c0] = o00;
  Om[(size_t)r0 * NC + c0 + 1] = o01;
  Om[(size_t)(r0 + 1) * NC + c0] = o10;
  Om[(size_t)(r0 + 1) * NC + c0 + 1] = o11;
  if (ti != tj) {   // mirror tile via LDS transpose (reuse As)
    As[ty * 2][tx * 2] = o00;
    As[ty * 2][tx * 2 + 1] = o01;
    As[ty * 2 + 1][tx * 2] = o10;
    As[ty * 2 + 1][tx * 2 + 1] = o11;
    __syncthreads();
    for (int idx = tid; idx < 1024; idx += 256) {
      int r = idx >> 5, cc = idx & 31;
      Om[(size_t)(j0 + r) * NC + i0 + cc] = As[cc][r];
    }
  }
}

// ---------------------------------------------------------------------------
// 5. finalize: Mh/Ml[m] = fp16-split( Z[m]*sqrt(scale[m]) * 512 )  (whiten B
//    operand, k-contiguous rows; Z symmetric so row-major serves both roles);
//    sqr_s[b] = Y_s / sqrt(scale) in fp32 for coloring.
__global__ __launch_bounds__(256) void finalize_kernel(const float* __restrict__ Yf,
                                                       const float* __restrict__ Zf,
                                                       const double* __restrict__ scaleArr,
                                                       _Float16* __restrict__ Mh,
                                                       _Float16* __restrict__ Ml,
                                                       float* __restrict__ sqr_s) {
  int which = blockIdx.y;
  int idx = blockIdx.x * 256 + threadIdx.x;   // [0, NM*NC*NC)
  int m = idx >> 16;
  int ij = idx & 65535;
  if (which == 0) {
    double s = sqrt(scaleArr[m]);
    float v = (float)((double)Zf[idx] * s) * SPLIT_SCALE;
    _Float16 h = (_Float16)v;
    Mh[idx] = h;
    Ml[idx] = (_Float16)(v - (float)h);
  } else {
    if (m >= NB) return;
    double s = sqrt(scaleArr[4 + m]);
    sqr_s[idx] = (float)((double)Yf[(size_t)(4 + m) * 65536 + ij] / s);
  }
}

// ---------------------------------------------------------------------------
// 6. MFMA whiten (replaces fp32 whiten + split pass):
//    out[p][c] = sum_k CzT[p][k] * M[k][c], 3-term fp16 split, 128x128 tile,
//    4 waves each 64x64, BK=32, global_load_lds staging (dmat structure).
//    acc = whitened * 512^2. Epilogue fuses the old split_kernel:
//      hi/lo = split(acc/512)  -> Ahi/Alo (style) or Bhi/Blo (content)
//      nswT fp32 + ssq partials (style only; deterministic 4-slot partials).
__global__ __launch_bounds__(256) void whiten_mfma_kernel(const _Float16* __restrict__ CzhT,
                                                          const _Float16* __restrict__ CzlT,
                                                          const _Float16* __restrict__ Mh,
                                                          const _Float16* __restrict__ Ml,
                                                          _Float16* __restrict__ BhiT,
                                                          _Float16* __restrict__ BloT,
                                                          _Float16* __restrict__ AhiT,
                                                          _Float16* __restrict__ AloT,
                                                          float* __restrict__ nswT,
                                                          float* __restrict__ ssqp) {
  __shared__ _Float16 sAh[128 * 32], sAl[128 * 32], sBh[128 * 32], sBl[128 * 32];
  int m = blockIdx.z;
  const _Float16* Ah = CzhT + (size_t)m * NP * NC;
  const _Float16* Al = CzlT + (size_t)m * NP * NC;
  const _Float16* Bh = Mh + (size_t)m * NC * NC;
  const _Float16* Bl = Ml + (size_t)m * NC * NC;
  int p0 = blockIdx.x * 128, c0 = blockIdx.y * 128;
  int tid = threadIdx.x, lane = tid & 63;
  int mm = lane & 15, quad = lane >> 4;
  int w = tid >> 6, qr = w & 1, qc = w >> 1;
  f4v acc[4][4] = {};
  for (int step = 0; step < NC / 32; step++) {
    int k0 = step * 32;
    __syncthreads();
#pragma unroll
    for (int i = 0; i < 2; i++) {
      int seg = i * 256 + tid;
      int row = seg >> 2, koff = (seg & 3) * 8;
      int sbase = (i * 256 + (tid & ~63)) * 8;   // wave-uniform
      GLD16(&sAh[sbase], Ah + (size_t)(p0 + row) * NC + k0 + koff);
      GLD16(&sAl[sbase], Al + (size_t)(p0 + row) * NC + k0 + koff);
      GLD16(&sBh[sbase], Bh + (size_t)(c0 + row) * NC + k0 + koff);
      GLD16(&sBl[sbase], Bl + (size_t)(c0 + row) * NC + k0 + koff);
    }
    __syncthreads();   // drains vmcnt (global_load_lds) per barrier semantics
    h8v afh[4], afl[4], bfh[4], bfl[4];
#pragma unroll
    for (int t = 0; t < 4; t++) {
      int ra = (qr * 64 + t * 16 + mm) * 32 + quad * 8;
      afh[t] = *(const h8v*)&sAh[ra];
      afl[t] = *(const h8v*)&sAl[ra];
      int rb = (qc * 64 + t * 16 + mm) * 32 + quad * 8;
      bfh[t] = *(const h8v*)&sBh[rb];
      bfl[t] = *(const h8v*)&sBl[rb];
    }
#pragma unroll
    for (int tr = 0; tr < 4; tr++)
#pragma unroll
      for (int tc = 0; tc < 4; tc++) {
        acc[tr][tc] = __builtin_amdgcn_mfma_f32_16x16x32_f16(afh[tr], bfh[tc], acc[tr][tc], 0, 0, 0);
        acc[tr][tc] = __builtin_amdgcn_mfma_f32_16x16x32_f16(afh[tr], bfl[tc], acc[tr][tc], 0, 0, 0);
        acc[tr][tc] = __builtin_amdgcn_mfma_f32_16x16x32_f16(afl[tr], bfh[tc], acc[tr][tc], 0, 0, 0);
      }
  }
  int feat = m >> 2, b = m & 3;
  _Float16* oh = (feat ? AhiT : BhiT) + (size_t)b * NP * NC;
  _Float16* ol = (feat ? AloT : BloT) + (size_t)b * NP * NC;
  float* nsw = nswT + (size_t)b * NP * NC;
  const float DSPL = 1.0f / SPLIT_SCALE;          // acc*DSPL = whitened*512
  const float DESC = DSPL * DSPL;                 // acc*DESC = whitened
  // C/D layout: col = lane&15, row = quad*4 + reg  [verified mapping]
#pragma unroll
  for (int tr = 0; tr < 4; tr++)
#pragma unroll
    for (int r = 0; r < 4; r++) {
      int p = p0 + qr * 64 + tr * 16 + quad * 4 + r;
      float ps = 0.f;
#pragma unroll
      for (int tc = 0; tc < 4; tc++) {
        int c = c0 + qc * 64 + tc * 16 + mm;
        float a = acc[tr][tc][r];
        float sv = a * DSPL;
        _Float16 hh = (_Float16)sv;
        size_t o = (size_t)p * NC + c;
        oh[o] = hh;
        ol[o] = (_Float16)(sv - (float)hh);
        if (feat) {
          float v = a * DESC;
          nsw[o] = v;
          ps += v * v;
        }
      }
      if (feat) {   // 16-lane (mm) reduce -> one deterministic partial per p
        ps += __shfl_xor(ps, 1);
        ps += __shfl_xor(ps, 2);
        ps += __shfl_xor(ps, 4);
        ps += __shfl_xor(ps, 8);
        if (mm == 0)
          ssqp[((size_t)(blockIdx.y * 2 + qc) * NB + b) * NP + p] = ps;
      }
    }
}

// ---------------------------------------------------------------------------
// 7. knorm box from the 4 deterministic ssq partials per (b,p)
__global__ __launch_bounds__(256) void rknorm_kernel(const float* __restrict__ ssqp,
                                                     float* __restrict__ rk) {
  int idx = blockIdx.x * 256 + threadIdx.x;
  int b = idx >> 12, p = idx & 4095;
  int pi = p >> 6, pj = p & 63;
  float s = 0.f;
#pragma unroll
  for (int d = -1; d <= 1; d++)
#pragma unroll
    for (int e = -1; e <= 1; e++) {
      if ((unsigned)(pi + d) < 64u && (unsigned)(pj + e) < 64u) {
        int q = b * NP + (pi + d) * 64 + pj + e;
#pragma unroll
        for (int sl = 0; sl < 4; sl++) s += ssqp[(size_t)sl * NB * NP + q];
      }
    }
  rk[idx] = 1.0f / sqrtf(s);
}

// ---------------------------------------------------------------------------
// 8. MFMA: D[p][x] = sum_c A[p][c]*B[x][c] via 3-term fp16 split (hh, hl, lh).
//    128x128 tile/block, 4 waves each 64x64 (4x4 of mfma_f32_16x16x32_f16),
//    BK=32, global_load_lds 16B staging.
__global__ __launch_bounds__(256) void dmat_kernel(const _Float16* __restrict__ AhiT,
                                                   const _Float16* __restrict__ AloT,
                                                   const _Float16* __restrict__ BhiT,
                                                   const _Float16* __restrict__ BloT,
                                                   float* __restrict__ D, int b) {
  __shared__ _Float16 sAh[128 * 32], sAl[128 * 32], sBh[128 * 32], sBl[128 * 32];
  const _Float16* Ah = AhiT + (size_t)b * NP * NC;
  const _Float16* Al = AloT + (size_t)b * NP * NC;
  const _Float16* Bh = BhiT + (size_t)b * NP * NC;
  const _Float16* Bl = BloT + (size_t)b * NP * NC;
  int p0 = blockIdx.x * 128, x0 = blockIdx.y * 128;
  int tid = threadIdx.x, lane = tid & 63;
  int m = lane & 15, quad = lane >> 4;
  int w = tid >> 6, qr = w & 1, qc = w >> 1;
  f4v acc[4][4] = {};
  for (int step = 0; step < NC / 32; step++) {
    int c0 = step * 32;
    __syncthreads();
#pragma unroll
    for (int i = 0; i < 2; i++) {
      int seg = i * 256 + tid;
      int row = seg >> 2, koff = (seg & 3) * 8;
      int sbase = (i * 256 + (tid & ~63)) * 8;   // wave-uniform
      GLD16(&sAh[sbase], Ah + (size_t)(p0 + row) * NC + c0 + koff);
      GLD16(&sAl[sbase], Al + (size_t)(p0 + row) * NC + c0 + koff);
      GLD16(&sBh[sbase], Bh + (size_t)(x0 + row) * NC + c0 + koff);
      GLD16(&sBl[sbase], Bl + (size_t)(x0 + row) * NC + c0 + koff);
    }
    __syncthreads();   // drains vmcnt (global_load_lds) per barrier semantics
    h8v afh[4], afl[4], bfh[4], bfl[4];
#pragma unroll
    for (int t = 0; t < 4; t++) {
      int ra = (qr * 64 + t * 16 + m) * 32 + quad * 8;
      afh[t] = *(const h8v*)&sAh[ra];
      afl[t] = *(const h8v*)&sAl[ra];
      int rb = (qc * 64 + t * 16 + m) * 32 + quad * 8;
      bfh[t] = *(const h8v*)&sBh[rb];
      bfl[t] = *(const h8v*)&sBl[rb];
    }
#pragma unroll
    for (int tr = 0; tr < 4; tr++)
#pragma unroll
      for (int tc = 0; tc < 4; tc++) {
        acc[tr][tc] = __builtin_amdgcn_mfma_f32_16x16x32_f16(afh[tr], bfh[tc], acc[tr][tc], 0, 0, 0);
        acc[tr][tc] = __builtin_amdgcn_mfma_f32_16x16x32_f16(afh[tr], bfl[tc], acc[tr][tc], 0, 0, 0);
        acc[tr][tc] = __builtin_amdgcn_mfma_f32_16x16x32_f16(afl[tr], bfh[tc], acc[tr][tc], 0, 0, 0);
      }
  }
  // C/D layout: col = lane&15, row = quad*4 + reg  [verified mapping]
#pragma unroll
  for (int tr = 0; tr < 4; tr++)
#pragma unroll
    for (int tc = 0; tc < 4; tc++)
#pragma unroll
      for (int r = 0; r < 4; r++) {
        int row = p0 + qr * 64 + tr * 16 + quad * 4 + r;
        int col = x0 + qc * 64 + tc * 16 + m;
        D[(size_t)row * NP + col] = acc[tr][tc][r];
      }
}

// ---------------------------------------------------------------------------
// 9. score: shifted-sum + slab-local argmax, cross-slab reduction via packed
//    u64 atomicMax: key = (sortable(score)<<32) | ~p (first-max tie rule).
//    Flat-index identity: D[p+off][x+off] = Dflat[p*NP + x + off*(NP+1)], so
//    the 9 taps sit at constant flat offsets from p*NP+x. Masks hoisted:
//    xm[q] and the pi+d row check are slab-constant (PSLAB=32 is 64-aligned);
//    the only p-dependent mask (pj+e col boundary) fires solely at pj==0
//    (e=-1) or pj==63 (e=+1) == first/last p of the slab -> peeled. Masked
//    taps read base+0 (in-bounds) times weight 0 — bit-identical math.
__global__ __launch_bounds__(256) void score_kernel(const float* __restrict__ D,
                                                    const float* __restrict__ rk,
                                                    unsigned long long* __restrict__ packed,
                                                    int b) {
  int x = blockIdx.x * 256 + threadIdx.x;
  int slab = blockIdx.y;
  int xi = x >> 6, xj = x & 63;
  int p0 = slab * PSLAB;
  int pi = p0 >> 6;                 // constant across the slab
  const float* rkb = rk + (size_t)b * NP;
  float w[9];
  int xco[9];                       // x + flat tap offset (loop-invariant VGPRs)
#pragma unroll
  for (int q = 0; q < 9; q++) {
    int d = q / 3 - 1, e = q % 3 - 1;
    bool ok = ((unsigned)(xi + d) < 64u) && ((unsigned)(xj + e) < 64u) &&
              ((unsigned)(pi + d) < 64u);
    w[q] = ok ? 1.0f : 0.0f;
    xco[q] = x + (ok ? (d * 64 + e) * (NP + 1) : 0);
  }
  float best = -1e30f;
  int bi = 0;
  // fast interior step: no masking needed (all pj+e valid)
  auto step = [&](int p) {
    const float* Dp = D + (size_t)p * NP;   // wave-uniform -> SGPR base
    float acc = 0.f;
#pragma unroll
    for (int q = 0; q < 9; q++) acc += w[q] * Dp[(ptrdiff_t)xco[q]];
    float s = acc * rkb[p];
    if (s > best) { best = s; bi = p; }
  };
  // boundary step: additionally mask pj+e
  auto stepb = [&](int p) {
    int pj = p & 63;
    const float* Dp = D + (size_t)p * NP;
    float acc = 0.f;
#pragma unroll
    for (int q = 0; q < 9; q++) {
      int e = q % 3 - 1;
      bool okc = (unsigned)(pj + e) < 64u;
      float wq = okc ? w[q] : 0.f;
      acc += wq * Dp[(ptrdiff_t)(okc ? xco[q] : x)];
    }
    float s = acc * rkb[p];
    if (s > best) { best = s; bi = p; }
  };
  if ((p0 & 63) == 0) {             // slab starts at pj==0: peel first p
    stepb(p0);
    for (int p = p0 + 1; p < p0 + PSLAB; p++) step(p);
  } else {                          // slab ends at pj==63: peel last p
    for (int p = p0; p < p0 + PSLAB - 1; p++) step(p);
    stepb(p0 + PSLAB - 1);
  }
  unsigned long long key = ((unsigned long long)sortable_f32(best) << 32) |
                           (unsigned)(~(unsigned)bi);
  atomicMax(&packed[(size_t)b * NP + x], key);
}

// ---------------------------------------------------------------------------
// 11. gather-form overlap-add reassembly, divided by deconv norm (reads nswT [p][c]).
//     Unpacks argmax p from the packed u64 (p = ~lo & 4095).
__global__ __launch_bounds__(256) void reassemble_kernel(const float* __restrict__ nswT,
                                                         const unsigned long long* __restrict__ packed,
                                                         float* __restrict__ reass) {
  int by = blockIdx.x;       // b*NP + y
  int b = by >> 12, y = by & 4095;
  int yi = y >> 6, yj = y & 63;
  int t = threadIdx.x;       // channel
  float acc = 0.f;
#pragma unroll
  for (int oi = 0; oi < 3; oi++)
#pragma unroll
    for (int oj = 0; oj < 3; oj++) {
      int xi = yi + 1 - oi, xj = yj + 1 - oj;
      if ((unsigned)xi < 64u && (unsigned)xj < 64u) {
        unsigned long long v = packed[(size_t)b * NP + xi * 64 + xj];
        int p = (int)((~(unsigned)(v & 0xFFFFFFFFull)) & 4095u);
        int qi = (p >> 6) + oi - 1, qj = (p & 63) + oj - 1;
        if ((unsigned)qi < 64u && (unsigned)qj < 64u)
          acc += nswT[((size_t)b * NP + qi * 64 + qj) * NC + t];
      }
    }
  int cy = (yi == 0 || yi == 63) ? 2 : 3;
  int cx = (yj == 0 || yj == 63) ? 2 : 3;
  reass[((size_t)b * NP + y) * NC + t] = acc / (float)(cy * cx);
}

// ---------------------------------------------------------------------------
// 12. coloring: out[b][c][y] = sum_j sqr_s[b][c][j]*reass[b][y][j] + mean_s[b][c].
//     sqr_s symmetric -> As staged from rows (float4, conflict-free).
__global__ __launch_bounds__(256) void coloring_kernel(const float* __restrict__ sqr_s,
                                                       const float* __restrict__ reass,
                                                       const float* __restrict__ mean,
                                                       float* __restrict__ out) {
  int b = blockIdx.z;
  const float* A = sqr_s + (size_t)b * NC * NC;
  const float* Bm = reass + (size_t)b * NP * NC;
  const float* mu = mean + (size_t)NB * NC + b * NC;
  float* dst = out + (size_t)b * NC * NP;
  int c0 = blockIdx.x * 64, y0 = blockIdx.y * 64;
  __shared__ float As[32][68];   // [j][c], float4 rows
  __shared__ float Bs[32][66];   // [j][y], transposed scalar writes
  int tid = threadIdx.x, tx = tid & 15, ty = tid >> 4;
  float acc[4][4] = {};
  for (int k0 = 0; k0 < NC; k0 += 32) {
    for (int idx = tid; idx < 512; idx += 256) {
      int kk = idx >> 4, r4 = (idx & 15) * 4;   // A symmetric: row k, cols c
      *(float4*)&As[kk][r4] = *(const float4*)&A[(size_t)(k0 + kk) * NC + c0 + r4];
    }
    for (int idx = tid; idx < 2048; idx += 256) {
      int r = idx >> 5, kk = idx & 31;
      Bs[kk][r] = Bm[(size_t)(y0 + r) * NC + k0 + kk];
    }
    __syncthreads();
#pragma unroll
    for (int kk = 0; kk < 32; kk++) {
      float4 av = *(const float4*)&As[kk][ty * 4];
      float a[4] = {av.x, av.y, av.z, av.w};
      float bb[4];
      *(float2*)&bb[0] = *(const float2*)&Bs[kk][tx * 4];
      *(float2*)&bb[2] = *(const float2*)&Bs[kk][tx * 4 + 2];
#pragma unroll
      for (int i = 0; i < 4; i++)
#pragma unroll
        for (int j = 0; j < 4; j++) acc[i][j] += a[i] * bb[j];
    }
    __syncthreads();
  }
#pragma unroll
  for (int i = 0; i < 4; i++) {
    float m = mu[c0 + ty * 4 + i];
    float4 v = make_float4(acc[i][0] + m, acc[i][1] + m, acc[i][2] + m, acc[i][3] + m);
    *(float4*)&dst[(size_t)(c0 + ty * 4 + i) * NP + y0 + tx * 4] = v;
  }
}

// ---------------------------------------------------------------------------
extern "C" void kernel_launch(void* const* d_in, const int* in_sizes, int n_in,
                              void* d_out, int out_size, void* d_ws, size_t ws_size,
                              hipStream_t stream) {
  (void)in_sizes; (void)n_in; (void)out_size; (void)ws_size;
  const float* content = (const float*)d_in[0];
  const float* style = (const float*)d_in[1];
  float* out = (float*)d_out;

  // workspace carve-up (256B aligned)
  char* w = (char*)d_ws;
  auto alloc = [&](size_t bytes) -> void* {
    void* p = (void*)w;
    w += (bytes + 255) & ~(size_t)255;
    return p;
  };
  float* mean = (float*)alloc(2 * NB * NC * sizeof(float));
  double* pcov = (double*)alloc((size_t)KSPLIT * NM * NC * NC * sizeof(double));  // 32MB
  double* cov = (double*)alloc((size_t)NM * NC * NC * sizeof(double));
  float* Y0 = (float*)alloc((size_t)NM * NC * NC * sizeof(float));   // fp32 NS state
  float* Z0 = (float*)alloc((size_t)NM * NC * NC * sizeof(float));
  float* Y1 = (float*)alloc((size_t)NM * NC * NC * sizeof(float));
  float* Z1 = (float*)alloc((size_t)NM * NC * NC * sizeof(float));
  float* T = (float*)alloc((size_t)NM * NC * NC * sizeof(float));
  double* scaleArr = (double*)alloc(NM * sizeof(double));
  _Float16* Mh = (_Float16*)alloc((size_t)NM * NC * NC * sizeof(_Float16));  // 1MB
  _Float16* Ml = (_Float16*)alloc((size_t)NM * NC * NC * sizeof(_Float16));  // 1MB
  float* sqr_s = (float*)alloc((size_t)NB * NC * NC * sizeof(float));
  float* nswT = (float*)alloc((size_t)NB * NP * NC * sizeof(float));  // [p][c]
  float* ssqp = (float*)alloc((size_t)4 * NB * NP * sizeof(float));   // 4 partial slots
  float* rk = (float*)alloc((size_t)NB * NP * sizeof(float));
  unsigned long long* packed =
      (unsigned long long*)alloc((size_t)NB * NP * sizeof(unsigned long long));  // 128KB
  float* Dbuf = (float*)alloc((size_t)NP * NP * sizeof(float));  // 64MB, multi-overlaid:
  float* reass = Dbuf + (size_t)NB * NP * NC;          // [16MB, 32MB), used after score loop
  // raw fp16 split overlays Dbuf[0,32MB) — dead before dmat first writes Dbuf
  _Float16* Czh = (_Float16*)Dbuf;                       // 16MB: NM*NC*NP fp16 [k][p]
  _Float16* Czl = Czh + (size_t)NM * NC * NP;            // 16MB
  // transposed raw split overlays Dbuf[32MB,64MB) — also dead before dmat
  _Float16* CzhT = Czh + (size_t)2 * NM * NC * NP;       // 16MB: [p][k]
  _Float16* CzlT = CzhT + (size_t)NM * NC * NP;          // 16MB
  // whitened fp16 split arrays overlay pcov (dead after cov_reduce): 4 x 8MB
  _Float16* AhiT = (_Float16*)pcov;
  _Float16* AloT = AhiT + (size_t)NB * NP * NC;
  _Float16* BhiT = AloT + (size_t)NB * NP * NC;
  _Float16* BloT = BhiT + (size_t)NB * NP * NC;

  // 1-2: fused mean + raw split, then MFMA syrk cov
  meansplit_kernel<<<2 * NB * NC, 256, 0, stream>>>(content, style, mean, Czh, Czl);
  cov_mfma_kernel<<<dim3(10, KSPLIT, NM), 256, 0, stream>>>(Czh, Czl, pcov);
  cov_reduce_kernel<<<NM * NC * NC / 256, 256, 0, stream>>>(pcov, cov);

  // 2c: transpose raw split to [p][k] for the MFMA whiten A-operand
  transpose_kernel<<<dim3(NP / 64, NC / 64, NM), 256, 0, stream>>>(Czh, Czl, CzhT, CzlT);

  // 3-4: Newton-Schulz inverse/forward sqrt (fp32, Gershgorin-scaled,
  //      symmetric upper-tri tiles only)
  bound_init_kernel<<<NM, 256, 0, stream>>>(cov, Y0, Z0, scaleArr);
  float *Ya = Y0, *Za = Z0, *Yb = Y1, *Zb = Z1;
  for (int it = 0; it < NS_ITERS; it++) {
    ns_t_kernel<<<dim3(NTILE8, 1, NM), 256, 0, stream>>>(Za, Ya, T);
    ns_upd_kernel<<<dim3(NTILE8, 1, NM * 2), 256, 0, stream>>>(Ya, Za, T, Yb, Zb);
    float* tmp;
    tmp = Ya; Ya = Yb; Yb = tmp;
    tmp = Za; Za = Zb; Zb = tmp;
  }
  finalize_kernel<<<dim3(NM * NC * NC / 256, 2), 256, 0, stream>>>(Ya, Za, scaleArr,
                                                                   Mh, Ml, sqr_s);

  // 6: MFMA whiten both features with fused fp16-split epilogue + style ssq
  whiten_mfma_kernel<<<dim3(NP / 128, NC / 128, NM), 256, 0, stream>>>(
      CzhT, CzlT, Mh, Ml, BhiT, BloT, AhiT, AloT, nswT, ssqp);

  // 7: knorm box from ssq partials
  rknorm_kernel<<<NB * NP / 256, 256, 0, stream>>>(ssqp, rk);

  // 8-9: zero packed argmax keys, then per batch: D = A B^T (MFMA fp16
  //      3-term), score with fused atomicMax argmax
  hipMemsetAsync(packed, 0, (size_t)NB * NP * sizeof(unsigned long long), stream);
  for (int b = 0; b < NB; b++) {
    dmat_kernel<<<dim3(NP / 128, NP / 128), 256, 0, stream>>>(AhiT, AloT, BhiT, BloT, Dbuf, b);
    score_kernel<<<dim3(NP / 256, NSLAB), 256, 0, stream>>>(Dbuf, rk, packed, b);
  }

  // 11: reassembly (gather form) straight from nswT, unpacking argmax keys
  reassemble_kernel<<<NB * NP, 256, 0, stream>>>(nswT, packed, reass);

  // 12: coloring straight into d_out (style_strength == 1.0)
  coloring_kernel<<<dim3(NC / 64, NP / 64, NB), 256, 0, stream>>>(sqr_s, reass, mean, out);
}

// Round 3
// 839.587 us; speedup vs baseline: 1.2614x; 1.2614x over previous
//
#include <hip/hip_runtime.h>
#include <stdint.h>
#include <stddef.h>

// Problem constants
constexpr int NB = 4;      // batch
constexpr int NC = 256;    // channels
constexpr int HW = 64;     // spatial side
constexpr int NP = 4096;   // HW*HW
constexpr int NM = 8;      // matrices for Newton-Schulz: 2 feats x 4 batches
constexpr int NS_ITERS = 7;       // lam_scaled ~0.135 -> residual saturates fp32 eps at 7
constexpr int NSLAB = 128;        // score slabs (combine fused via atomicMax)
constexpr int PSLAB = NP / NSLAB; // 32
constexpr int KSPLIT = 8;         // cov K-split
constexpr int KCHUNK = NP / KSPLIT; // 512
constexpr int NTILE8 = 36;        // upper-tri 32-tiles in 8x8 grid (NS symmetric)

// fp16 Markidis split (bf16 2-split caused argmax flips). Pre-scale by 512
// keeps lo out of fp16-subnormal range; uniform scaling is argmax-invariant
// for D, and is divided back out for cov.
constexpr float SPLIT_SCALE = 512.0f;
constexpr double COV_DESCALE = 1.0 / ((double)SPLIT_SCALE * (double)SPLIT_SCALE);

typedef __attribute__((ext_vector_type(8))) _Float16 h8v;  // 8 fp16 (4 VGPRs)
typedef __attribute__((ext_vector_type(4))) _Float16 h4v;  // 4 fp16 (8B store)
typedef __attribute__((ext_vector_type(4))) float f4v;     // MFMA acc

// async global->LDS, 16B per lane; lds arg must be wave-uniform
#define GLD16(lds, g)                                                        \
  __builtin_amdgcn_global_load_lds(                                          \
      (const __attribute__((address_space(1))) void*)(g),                    \
      (__attribute__((address_space(3))) void*)(lds), 16, 0, 0)

// monotone float -> sortable u32 (finite inputs): order(f) == order(sortable(f))
__device__ inline unsigned sortable_f32(float f) {
  unsigned u = __float_as_uint(f);
  return (u & 0x80000000u) ? ~u : (u | 0x80000000u);
}

// ---------------------------------------------------------------------------
// 1. fused mean + raw fp16 split: (src-mu)*512 -> fp16 hi/lo in [c][p]
__global__ __launch_bounds__(256) void meansplit_kernel(const float* __restrict__ content,
                                                        const float* __restrict__ style,
                                                        float* __restrict__ mean,
                                                        _Float16* __restrict__ Czh,
                                                        _Float16* __restrict__ Czl) {
  int id = blockIdx.x;              // [0, 2*NB*NC) == m*NC + c
  int feat = id / (NB * NC);
  int bc = id % (NB * NC);
  const float* src = (feat ? style : content) + (size_t)bc * NP;
  int tid = threadIdx.x;
  float s = 0.f;
  for (int i = tid; i < NP; i += 256) s += src[i];
  __shared__ float red[256];
  red[tid] = s;
  __syncthreads();
  for (int st = 128; st > 0; st >>= 1) {
    if (tid < st) red[tid] += red[tid + st];
    __syncthreads();
  }
  float mu = red[0] * (1.0f / NP);
  if (tid == 0) mean[id] = mu;
  _Float16* oh = Czh + (size_t)id * NP;
  _Float16* ol = Czl + (size_t)id * NP;
  for (int f4 = tid; f4 < NP / 4; f4 += 256) {
    float4 v = *(const float4*)&src[f4 * 4];
    float vv[4] = {v.x, v.y, v.z, v.w};
    h4v h, l;
#pragma unroll
    for (int q = 0; q < 4; q++) {
      float sv = (vv[q] - mu) * SPLIT_SCALE;
      _Float16 hh = (_Float16)sv;
      h[q] = hh;
      l[q] = (_Float16)(sv - (float)hh);
    }
    *(h4v*)&oh[f4 * 4] = h;
    *(h4v*)&ol[f4 * 4] = l;
  }
}

// ---------------------------------------------------------------------------
// 2. MFMA syrk cov: 64x64 upper-tri tiles, 4-term fp16 split, per-32-k fp64 fold
__global__ __launch_bounds__(256) void cov_mfma_kernel(const _Float16* __restrict__ Czh,
                                                       const _Float16* __restrict__ Czl,
                                                       double* __restrict__ pcov) {
  __shared__ _Float16 sAh[64 * 32], sAl[64 * 32], sBh[64 * 32], sBl[64 * 32];
  int m = blockIdx.z;
  int t = blockIdx.x, ti = 0, rem = t;
  while (rem >= 4 - ti) { rem -= 4 - ti; ti++; }
  int tj = ti + rem;
  int i0 = ti * 64, j0 = tj * 64;
  const _Float16* Ah = Czh + ((size_t)m * NC + i0) * NP;
  const _Float16* Al = Czl + ((size_t)m * NC + i0) * NP;
  const _Float16* Bh = Czh + ((size_t)m * NC + j0) * NP;
  const _Float16* Bl = Czl + ((size_t)m * NC + j0) * NP;
  int k0base = blockIdx.y * KCHUNK;
  int tid = threadIdx.x, lane = tid & 63;
  int mm = lane & 15, quad = lane >> 4;
  int w = tid >> 6, qr = w & 1, qc = w >> 1;
  double dacc[2][2][4] = {};
  for (int step = 0; step < KCHUNK / 32; step++) {
    int k0 = k0base + step * 32;
    __syncthreads();
    {
      int row = tid >> 2, koff = (tid & 3) * 8;
      int sbase = (tid & ~63) * 8;   // wave-uniform
      GLD16(&sAh[sbase], Ah + (size_t)row * NP + k0 + koff);
      GLD16(&sAl[sbase], Al + (size_t)row * NP + k0 + koff);
      GLD16(&sBh[sbase], Bh + (size_t)row * NP + k0 + koff);
      GLD16(&sBl[sbase], Bl + (size_t)row * NP + k0 + koff);
    }
    __syncthreads();   // drains vmcnt per barrier semantics
    h8v afh[2], afl[2], bfh[2], bfl[2];
#pragma unroll
    for (int tt = 0; tt < 2; tt++) {
      int ra = (qr * 32 + tt * 16 + mm) * 32 + quad * 8;
      afh[tt] = *(const h8v*)&sAh[ra];
      afl[tt] = *(const h8v*)&sAl[ra];
      int rb = (qc * 32 + tt * 16 + mm) * 32 + quad * 8;
      bfh[tt] = *(const h8v*)&sBh[rb];
      bfl[tt] = *(const h8v*)&sBl[rb];
    }
    f4v acc[2][2] = {};
#pragma unroll
    for (int tr = 0; tr < 2; tr++)
#pragma unroll
      for (int tc = 0; tc < 2; tc++) {
        acc[tr][tc] = __builtin_amdgcn_mfma_f32_16x16x32_f16(afh[tr], bfh[tc], acc[tr][tc], 0, 0, 0);
        acc[tr][tc] = __builtin_amdgcn_mfma_f32_16x16x32_f16(afh[tr], bfl[tc], acc[tr][tc], 0, 0, 0);
        acc[tr][tc] = __builtin_amdgcn_mfma_f32_16x16x32_f16(afl[tr], bfh[tc], acc[tr][tc], 0, 0, 0);
        acc[tr][tc] = __builtin_amdgcn_mfma_f32_16x16x32_f16(afl[tr], bfl[tc], acc[tr][tc], 0, 0, 0);
      }
#pragma unroll
    for (int tr = 0; tr < 2; tr++)
#pragma unroll
      for (int tc = 0; tc < 2; tc++)
#pragma unroll
        for (int r = 0; r < 4; r++) dacc[tr][tc][r] += (double)acc[tr][tc][r];
  }
  double* dst = pcov + ((size_t)blockIdx.y * NM + m) * NC * NC;
  // C/D layout: col = lane&15, row = quad*4 + reg  [verified mapping]
#pragma unroll
  for (int tr = 0; tr < 2; tr++)
#pragma unroll
    for (int tc = 0; tc < 2; tc++)
#pragma unroll
      for (int r = 0; r < 4; r++) {
        int row = i0 + qr * 32 + tr * 16 + quad * 4 + r;
        int col = j0 + qc * 32 + tc * 16 + mm;
        dst[(size_t)row * NC + col] = dacc[tr][tc][r];
      }
}

// 2b. sum K-split partials; mirror lower triangle from upper tiles; descale
__global__ __launch_bounds__(256) void cov_reduce_kernel(const double* __restrict__ pcov,
                                                         double* __restrict__ cov) {
  size_t idx = (size_t)blockIdx.x * 256 + threadIdx.x;  // [0, NM*NC*NC)
  int m = (int)(idx >> 16);
  int ij = (int)(idx & 65535);
  int i = ij >> 8, j = ij & 255;
  int src = ((i >> 6) <= (j >> 6)) ? ij : ((j << 8) | i);
  double s = 0;
  for (int k = 0; k < KSPLIT; k++)
    s += pcov[((size_t)k * NM + m) * 65536 + src];
  cov[idx] = s * COV_DESCALE;
}

// ---------------------------------------------------------------------------
// 2c. fp16 tile transpose: Czh/Czl [m][k][p] -> CzhT/CzlT [m][p][k], so the
//     MFMA whiten can read k-contiguous A fragments. 64x64 tiles, LDS pad 72
//     (144B stride: 8B-aligned, 2-way bank alias = free).
__global__ __launch_bounds__(256) void transpose_kernel(const _Float16* __restrict__ Czh,
                                                        const _Float16* __restrict__ Czl,
                                                        _Float16* __restrict__ CzhT,
                                                        _Float16* __restrict__ CzlT) {
  __shared__ unsigned short th[64][72], tl[64][72];
  int m = blockIdx.z;
  int p0 = blockIdx.x * 64, k0 = blockIdx.y * 64;
  int tid = threadIdx.x;
  const unsigned short* src_h = (const unsigned short*)(Czh + (size_t)m * NC * NP);
  const unsigned short* src_l = (const unsigned short*)(Czl + (size_t)m * NC * NP);
#pragma unroll
  for (int j = 0; j < 4; j++) {
    int e = j * 1024 + tid * 4;
    int kk = e >> 6, pp = e & 63;
    ushort4 vh = *(const ushort4*)&src_h[(size_t)(k0 + kk) * NP + p0 + pp];
    ushort4 vl = *(const ushort4*)&src_l[(size_t)(k0 + kk) * NP + p0 + pp];
    *(ushort4*)&th[kk][pp] = vh;
    *(ushort4*)&tl[kk][pp] = vl;
  }
  __syncthreads();
  unsigned short* dst_h = (unsigned short*)(CzhT + (size_t)m * NP * NC);
  unsigned short* dst_l = (unsigned short*)(CzlT + (size_t)m * NP * NC);
#pragma unroll
  for (int j = 0; j < 4; j++) {
    int e = j * 1024 + tid * 4;
    int pp = e >> 6, kk = e & 63;
    ushort4 vh, vl;
    vh.x = th[kk][pp];     vh.y = th[kk + 1][pp];
    vh.z = th[kk + 2][pp]; vh.w = th[kk + 3][pp];
    vl.x = tl[kk][pp];     vl.y = tl[kk + 1][pp];
    vl.z = tl[kk + 2][pp]; vl.w = tl[kk + 3][pp];
    *(ushort4*)&dst_h[(size_t)(p0 + pp) * NC + k0 + kk] = vh;
    *(ushort4*)&dst_l[(size_t)(p0 + pp) * NC + k0 + kk] = vl;
  }
}

// ---------------------------------------------------------------------------
// 3. Gershgorin bound; init Y = s*A, Z = I. Y/Z fp32 (coupled NS is stable,
//    err ~ cond*eps_f32 ~ 2e-7 rel). scaleArr stays fp64.
__global__ __launch_bounds__(256) void bound_init_kernel(const double* __restrict__ cov,
                                                         float* __restrict__ Y,
                                                         float* __restrict__ Z,
                                                         double* __restrict__ scaleArr) {
  int m = blockIdx.x;
  const double* A = cov + (size_t)m * NC * NC;
  int t = threadIdx.x;
  double s = 0;
  for (int i = 0; i < NC; i++) s += fabs(A[(size_t)i * NC + t]);   // coalesced
  __shared__ double red[256];
  red[t] = s;
  __syncthreads();
  for (int st = 128; st > 0; st >>= 1) {
    if (t < st) red[t] = fmax(red[t], red[t + st]);
    __syncthreads();
  }
  double scale = 1.0 / red[0];     // lam_max <= max abs row sum (rigorous upper bound)
  if (t == 0) scaleArr[m] = scale;
  float* Ym = Y + (size_t)m * NC * NC;
  float* Zm = Z + (size_t)m * NC * NC;
  for (int idx = t; idx < NC * NC; idx += 256) {
    Ym[idx] = (float)(A[idx] * scale);
    Zm[idx] = ((idx / NC) == (idx % NC)) ? 1.0f : 0.0f;
  }
}

// ---------------------------------------------------------------------------
// NS iterates are polynomials in symmetric A -> Y, Z, T, Y*T, T*Z all
// symmetric. Upper-tri 32x32 tiles only, mirror-write lower. fp32.

// 4a. T = Z * Y (fp32, upper-tri 32x32 tiles, 2x2 micro, mirrored writes)
__global__ __launch_bounds__(256) void ns_t_kernel(const float* __restrict__ Zin,
                                                   const float* __restrict__ Yin,
                                                   float* __restrict__ T) {
  int m = blockIdx.z;
  const float* Am = Zin + (size_t)m * NC * NC;
  const float* Bm = Yin + (size_t)m * NC * NC;
  float* Tm = T + (size_t)m * NC * NC;
  __shared__ float As[32][33];
  __shared__ float Bs[32][33];
  int tid = threadIdx.x, tx = tid & 15, ty = tid >> 4;
  int t = blockIdx.x, ti = 0, rem = t;     // unrank upper-tri tile (8x8 grid)
  while (rem >= 8 - ti) { rem -= 8 - ti; ti++; }
  int tj = ti + rem;
  int i0 = ti * 32, j0 = tj * 32;
  float a00 = 0, a01 = 0, a10 = 0, a11 = 0;
  for (int k0 = 0; k0 < NC; k0 += 32) {
    for (int idx = tid; idx < 1024; idx += 256) {
      int r = idx >> 5, cc = idx & 31;
      As[r][cc] = Am[(size_t)(i0 + r) * NC + k0 + cc];
      Bs[r][cc] = Bm[(size_t)(k0 + r) * NC + j0 + cc];
    }
    __syncthreads();
#pragma unroll
    for (int kk = 0; kk < 32; kk++) {
      float x0 = As[ty * 2][kk], x1 = As[ty * 2 + 1][kk];
      float y0 = Bs[kk][tx * 2], y1 = Bs[kk][tx * 2 + 1];
      a00 += x0 * y0; a01 += x0 * y1; a10 += x1 * y0; a11 += x1 * y1;
    }
    __syncthreads();
  }
  Tm[(size_t)(i0 + ty * 2) * NC + j0 + tx * 2] = a00;
  Tm[(size_t)(i0 + ty * 2) * NC + j0 + tx * 2 + 1] = a01;
  Tm[(size_t)(i0 + ty * 2 + 1) * NC + j0 + tx * 2] = a10;
  Tm[(size_t)(i0 + ty * 2 + 1) * NC + j0 + tx * 2 + 1] = a11;
  if (ti != tj) {   // mirror tile, coalesced via LDS transpose (reuse As)
    As[ty * 2][tx * 2] = a00;
    As[ty * 2][tx * 2 + 1] = a01;
    As[ty * 2 + 1][tx * 2] = a10;
    As[ty * 2 + 1][tx * 2 + 1] = a11;
    __syncthreads();
    for (int idx = tid; idx < 1024; idx += 256) {
      int r = idx >> 5, cc = idx & 31;
      Tm[(size_t)(j0 + r) * NC + i0 + cc] = As[cc][r];
    }
  }
}

// 4b. Yout = 1.5*Yin - 0.5*Yin*T ; Zout = 1.5*Zin - 0.5*T*Zin  (fp32)
__global__ __launch_bounds__(256) void ns_upd_kernel(const float* __restrict__ Yin,
                                                     const float* __restrict__ Zin,
                                                     const float* __restrict__ T,
                                                     float* __restrict__ Yout,
                                                     float* __restrict__ Zout) {
  int z = blockIdx.z;
  int m = z & 7, which = z >> 3;
  size_t off = (size_t)m * NC * NC;
  const float* Am = which == 0 ? (Yin + off) : (T + off);
  const float* Bm = which == 0 ? (T + off) : (Zin + off);
  const float* Sm = which == 0 ? (Yin + off) : (Zin + off);
  float* Om = which == 0 ? (Yout + off) : (Zout + off);
  __shared__ float As[32][33];
  __shared__ float Bs[32][33];
  int tid = threadIdx.x, tx = tid & 15, ty = tid >> 4;
  int t = blockIdx.x, ti = 0, rem = t;     // unrank upper-tri tile (8x8 grid)
  while (rem >= 8 - ti) { rem -= 8 - ti; ti++; }
  int tj = ti + rem;
  int i0 = ti * 32, j0 = tj * 32;
  float a00 = 0, a01 = 0, a10 = 0, a11 = 0;
  for (int k0 = 0; k0 < NC; k0 += 32) {
    for (int idx = tid; idx < 1024; idx += 256) {
      int r = idx >> 5, cc = idx & 31;
      As[r][cc] = Am[(size_t)(i0 + r) * NC + k0 + cc];
      Bs[r][cc] = Bm[(size_t)(k0 + r) * NC + j0 + cc];
    }
    __syncthreads();
#pragma unroll
    for (int kk = 0; kk < 32; kk++) {
      float x0 = As[ty * 2][kk], x1 = As[ty * 2 + 1][kk];
      float y0 = Bs[kk][tx * 2], y1 = Bs[kk][tx * 2 + 1];
      a00 += x0 * y0; a01 += x0 * y1; a10 += x1 * y0; a11 += x1 * y1;
    }
    __syncthreads();
  }
  int r0 = i0 + ty * 2, c0 = j0 + tx * 2;
  float o00 = 1.5f * Sm[(size_t)r0 * NC + c0] - 0.5f * a00;
  float o01 = 1.5f * Sm[(size_t)r0 * NC + c0 + 1] - 0.5f * a01;
  float o10 = 1.5f * Sm[(size_t)(r0 + 1) * NC + c0] - 0.5f * a10;
  float o11 = 1.5f * Sm[(size_t)(r0 + 1) * NC + c0 + 1] - 0.5f * a11;
  Om[(size_t)r0 * NC + c0] = o00;
  Om[(size_t)r0 * NC + c0 + 1] = o01;
  Om[(size_t)(r0 + 1) * NC + c0] = o10;
  Om[(size_t)(r0 + 1) * NC + c0 + 1] = o11;
  if (ti != tj) {   // mirror tile via LDS transpose (reuse As)
    As[ty * 2][tx * 2] = o00;
    As[ty * 2][tx * 2 + 1] = o01;
    As[ty * 2 + 1][tx * 2] = o10;
    As[ty * 2 + 1][tx * 2 + 1] = o11;
    __syncthreads();
    for (int idx = tid; idx < 1024; idx += 256) {
      int r = idx >> 5, cc = idx & 31;
      Om[(size_t)(j0 + r) * NC + i0 + cc] = As[cc][r];
    }
  }
}

// ---------------------------------------------------------------------------
// 5. finalize: Mh/Ml[m] = fp16-split( Z[m]*sqrt(scale[m]) * 512 )  (whiten B
//    operand, k-contiguous rows; Z symmetric so row-major serves both roles);
//    sqr_s[b] = Y_s / sqrt(scale) in fp32 for coloring.
__global__ __launch_bounds__(256) void finalize_kernel(const float* __restrict__ Yf,
                                                       const float* __restrict__ Zf,
                                                       const double* __restrict__ scaleArr,
                                                       _Float16* __restrict__ Mh,
                                                       _Float16* __restrict__ Ml,
                                                       float* __restrict__ sqr_s) {
  int which = blockIdx.y;
  int idx = blockIdx.x * 256 + threadIdx.x;   // [0, NM*NC*NC)
  int m = idx >> 16;
  int ij = idx & 65535;
  if (which == 0) {
    double s = sqrt(scaleArr[m]);
    float v = (float)((double)Zf[idx] * s) * SPLIT_SCALE;
    _Float16 h = (_Float16)v;
    Mh[idx] = h;
    Ml[idx] = (_Float16)(v - (float)h);
  } else {
    if (m >= NB) return;
    double s = sqrt(scaleArr[4 + m]);
    sqr_s[idx] = (float)((double)Yf[(size_t)(4 + m) * 65536 + ij] / s);
  }
}

// ---------------------------------------------------------------------------
// 6. MFMA whiten (replaces fp32 whiten + split pass):
//    out[p][c] = sum_k CzT[p][k] * M[k][c], 3-term fp16 split, 128x128 tile,
//    4 waves each 64x64, BK=32, global_load_lds staging (dmat structure).
//    acc = whitened * 512^2. Epilogue fuses the old split_kernel:
//      hi/lo = split(acc/512)  -> Ahi/Alo (style) or Bhi/Blo (content)
//      nswT fp32 + ssq partials (style only; deterministic 4-slot partials).
__global__ __launch_bounds__(256) void whiten_mfma_kernel(const _Float16* __restrict__ CzhT,
                                                          const _Float16* __restrict__ CzlT,
                                                          const _Float16* __restrict__ Mh,
                                                          const _Float16* __restrict__ Ml,
                                                          _Float16* __restrict__ BhiT,
                                                          _Float16* __restrict__ BloT,
                                                          _Float16* __restrict__ AhiT,
                                                          _Float16* __restrict__ AloT,
                                                          float* __restrict__ nswT,
                                                          float* __restrict__ ssqp) {
  __shared__ _Float16 sAh[128 * 32], sAl[128 * 32], sBh[128 * 32], sBl[128 * 32];
  int m = blockIdx.z;
  const _Float16* Ah = CzhT + (size_t)m * NP * NC;
  const _Float16* Al = CzlT + (size_t)m * NP * NC;
  const _Float16* Bh = Mh + (size_t)m * NC * NC;
  const _Float16* Bl = Ml + (size_t)m * NC * NC;
  int p0 = blockIdx.x * 128, c0 = blockIdx.y * 128;
  int tid = threadIdx.x, lane = tid & 63;
  int mm = lane & 15, quad = lane >> 4;
  int w = tid >> 6, qr = w & 1, qc = w >> 1;
  f4v acc[4][4] = {};
  for (int step = 0; step < NC / 32; step++) {
    int k0 = step * 32;
    __syncthreads();
#pragma unroll
    for (int i = 0; i < 2; i++) {
      int seg = i * 256 + tid;
      int row = seg >> 2, koff = (seg & 3) * 8;
      int sbase = (i * 256 + (tid & ~63)) * 8;   // wave-uniform
      GLD16(&sAh[sbase], Ah + (size_t)(p0 + row) * NC + k0 + koff);
      GLD16(&sAl[sbase], Al + (size_t)(p0 + row) * NC + k0 + koff);
      GLD16(&sBh[sbase], Bh + (size_t)(c0 + row) * NC + k0 + koff);
      GLD16(&sBl[sbase], Bl + (size_t)(c0 + row) * NC + k0 + koff);
    }
    __syncthreads();   // drains vmcnt (global_load_lds) per barrier semantics
    h8v afh[4], afl[4], bfh[4], bfl[4];
#pragma unroll
    for (int t = 0; t < 4; t++) {
      int ra = (qr * 64 + t * 16 + mm) * 32 + quad * 8;
      afh[t] = *(const h8v*)&sAh[ra];
      afl[t] = *(const h8v*)&sAl[ra];
      int rb = (qc * 64 + t * 16 + mm) * 32 + quad * 8;
      bfh[t] = *(const h8v*)&sBh[rb];
      bfl[t] = *(const h8v*)&sBl[rb];
    }
#pragma unroll
    for (int tr = 0; tr < 4; tr++)
#pragma unroll
      for (int tc = 0; tc < 4; tc++) {
        acc[tr][tc] = __builtin_amdgcn_mfma_f32_16x16x32_f16(afh[tr], bfh[tc], acc[tr][tc], 0, 0, 0);
        acc[tr][tc] = __builtin_amdgcn_mfma_f32_16x16x32_f16(afh[tr], bfl[tc], acc[tr][tc], 0, 0, 0);
        acc[tr][tc] = __builtin_amdgcn_mfma_f32_16x16x32_f16(afl[tr], bfh[tc], acc[tr][tc], 0, 0, 0);
      }
  }
  int feat = m >> 2, b = m & 3;
  _Float16* oh = (feat ? AhiT : BhiT) + (size_t)b * NP * NC;
  _Float16* ol = (feat ? AloT : BloT) + (size_t)b * NP * NC;
  float* nsw = nswT + (size_t)b * NP * NC;
  const float DSPL = 1.0f / SPLIT_SCALE;          // acc*DSPL = whitened*512
  const float DESC = DSPL * DSPL;                 // acc*DESC = whitened
  // C/D layout: col = lane&15, row = quad*4 + reg  [verified mapping]
#pragma unroll
  for (int tr = 0; tr < 4; tr++)
#pragma unroll
    for (int r = 0; r < 4; r++) {
      int p = p0 + qr * 64 + tr * 16 + quad * 4 + r;
      float ps = 0.f;
#pragma unroll
      for (int tc = 0; tc < 4; tc++) {
        int c = c0 + qc * 64 + tc * 16 + mm;
        float a = acc[tr][tc][r];
        float sv = a * DSPL;
        _Float16 hh = (_Float16)sv;
        size_t o = (size_t)p * NC + c;
        oh[o] = hh;
        ol[o] = (_Float16)(sv - (float)hh);
        if (feat) {
          float v = a * DESC;
          nsw[o] = v;
          ps += v * v;
        }
      }
      if (feat) {   // 16-lane (mm) reduce -> one deterministic partial per p
        ps += __shfl_xor(ps, 1);
        ps += __shfl_xor(ps, 2);
        ps += __shfl_xor(ps, 4);
        ps += __shfl_xor(ps, 8);
        if (mm == 0)
          ssqp[((size_t)(blockIdx.y * 2 + qc) * NB + b) * NP + p] = ps;
      }
    }
}

// ---------------------------------------------------------------------------
// 7. knorm box from the 4 deterministic ssq partials per (b,p)
__global__ __launch_bounds__(256) void rknorm_kernel(const float* __restrict__ ssqp,
                                                     float* __restrict__ rk) {
  int idx = blockIdx.x * 256 + threadIdx.x;
  int b = idx >> 12, p = idx & 4095;
  int pi = p >> 6, pj = p & 63;
  float s = 0.f;
#pragma unroll
  for (int d = -1; d <= 1; d++)
#pragma unroll
    for (int e = -1; e <= 1; e++) {
      if ((unsigned)(pi + d) < 64u && (unsigned)(pj + e) < 64u) {
        int q = b * NP + (pi + d) * 64 + pj + e;
#pragma unroll
        for (int sl = 0; sl < 4; sl++) s += ssqp[(size_t)sl * NB * NP + q];
      }
    }
  rk[idx] = 1.0f / sqrtf(s);
}

// ---------------------------------------------------------------------------
// 8. MFMA: D[p][x] = sum_c A[p][c]*B[x][c] via 3-term fp16 split (hh, hl, lh).
//    128x128 tile/block, 4 waves each 64x64 (4x4 of mfma_f32_16x16x32_f16),
//    BK=32, global_load_lds 16B staging.
__global__ __launch_bounds__(256) void dmat_kernel(const _Float16* __restrict__ AhiT,
                                                   const _Float16* __restrict__ AloT,
                                                   const _Float16* __restrict__ BhiT,
                                                   const _Float16* __restrict__ BloT,
                                                   float* __restrict__ D, int b) {
  __shared__ _Float16 sAh[128 * 32], sAl[128 * 32], sBh[128 * 32], sBl[128 * 32];
  const _Float16* Ah = AhiT + (size_t)b * NP * NC;
  const _Float16* Al = AloT + (size_t)b * NP * NC;
  const _Float16* Bh = BhiT + (size_t)b * NP * NC;
  const _Float16* Bl = BloT + (size_t)b * NP * NC;
  int p0 = blockIdx.x * 128, x0 = blockIdx.y * 128;
  int tid = threadIdx.x, lane = tid & 63;
  int m = lane & 15, quad = lane >> 4;
  int w = tid >> 6, qr = w & 1, qc = w >> 1;
  f4v acc[4][4] = {};
  for (int step = 0; step < NC / 32; step++) {
    int c0 = step * 32;
    __syncthreads();
#pragma unroll
    for (int i = 0; i < 2; i++) {
      int seg = i * 256 + tid;
      int row = seg >> 2, koff = (seg & 3) * 8;
      int sbase = (i * 256 + (tid & ~63)) * 8;   // wave-uniform
      GLD16(&sAh[sbase], Ah + (size_t)(p0 + row) * NC + c0 + koff);
      GLD16(&sAl[sbase], Al + (size_t)(p0 + row) * NC + c0 + koff);
      GLD16(&sBh[sbase], Bh + (size_t)(x0 + row) * NC + c0 + koff);
      GLD16(&sBl[sbase], Bl + (size_t)(x0 + row) * NC + c0 + koff);
    }
    __syncthreads();   // drains vmcnt (global_load_lds) per barrier semantics
    h8v afh[4], afl[4], bfh[4], bfl[4];
#pragma unroll
    for (int t = 0; t < 4; t++) {
      int ra = (qr * 64 + t * 16 + m) * 32 + quad * 8;
      afh[t] = *(const h8v*)&sAh[ra];
      afl[t] = *(const h8v*)&sAl[ra];
      int rb = (qc * 64 + t * 16 + m) * 32 + quad * 8;
      bfh[t] = *(const h8v*)&sBh[rb];
      bfl[t] = *(const h8v*)&sBl[rb];
    }
#pragma unroll
    for (int tr = 0; tr < 4; tr++)
#pragma unroll
      for (int tc = 0; tc < 4; tc++) {
        acc[tr][tc] = __builtin_amdgcn_mfma_f32_16x16x32_f16(afh[tr], bfh[tc], acc[tr][tc], 0, 0, 0);
        acc[tr][tc] = __builtin_amdgcn_mfma_f32_16x16x32_f16(afh[tr], bfl[tc], acc[tr][tc], 0, 0, 0);
        acc[tr][tc] = __builtin_amdgcn_mfma_f32_16x16x32_f16(afl[tr], bfh[tc], acc[tr][tc], 0, 0, 0);
      }
  }
  // C/D layout: col = lane&15, row = quad*4 + reg  [verified mapping]
#pragma unroll
  for (int tr = 0; tr < 4; tr++)
#pragma unroll
    for (int tc = 0; tc < 4; tc++)
#pragma unroll
      for (int r = 0; r < 4; r++) {
        int row = p0 + qr * 64 + tr * 16 + quad * 4 + r;
        int col = x0 + qc * 64 + tc * 16 + m;
        D[(size_t)row * NP + col] = acc[tr][tc][r];
      }
}

// ---------------------------------------------------------------------------
// 9. score: shifted-sum + slab-local argmax, cross-slab reduction via packed
//    u64 atomicMax: key = (sortable(score)<<32) | ~p (first-max tie rule).
//    Flat-index identity: D[p+off][x+off] = Dflat[p*NP + x + off*(NP+1)] ->
//    taps at constant flat offsets. Round-2 post-mortem: serial per-p loads
//    were latency-bound (VALUBusy 14%, all idle). Fix: batch 4 p's, issue all
//    36 tap loads into registers (static indices) BEFORE the FMA/compare
//    chain -> 36-wide MLP. The one boundary-p per slab (pj==0|63) gets its
//    corrected score precomputed and substituted at compare time; compares
//    run in increasing p order -> bit-identical argmax.
__global__ __launch_bounds__(256) void score_kernel(const float* __restrict__ D,
                                                    const float* __restrict__ rk,
                                                    unsigned long long* __restrict__ packed,
                                                    int b) {
  int x = blockIdx.x * 256 + threadIdx.x;
  int slab = blockIdx.y;
  int xi = x >> 6, xj = x & 63;
  int p0 = slab * PSLAB;
  int pi = p0 >> 6;                 // constant across the slab
  const float* rkb = rk + (size_t)b * NP;
  float w[9];
  int xco[9];                       // x + flat tap offset (loop-invariant VGPRs)
#pragma unroll
  for (int q = 0; q < 9; q++) {
    int d = q / 3 - 1, e = q % 3 - 1;
    bool ok = ((unsigned)(xi + d) < 64u) && ((unsigned)(xj + e) < 64u) &&
              ((unsigned)(pi + d) < 64u);
    w[q] = ok ? 1.0f : 0.0f;
    xco[q] = x + (ok ? (d * 64 + e) * (NP + 1) : 0);
  }
  // boundary p of this slab (exactly one: pj==0 for even slabs, 63 for odd);
  // compute its corrected score up front (col-boundary taps masked).
  int pb = (p0 & 63) ? (p0 + PSLAB - 1) : p0;
  float sb;
  {
    int pj = pb & 63;
    const float* Dp = D + (size_t)pb * NP;
    float acc = 0.f;
#pragma unroll
    for (int q = 0; q < 9; q++) {
      int e = q % 3 - 1;
      bool okc = (unsigned)(pj + e) < 64u;
      float wq = okc ? w[q] : 0.f;
      acc += wq * Dp[(ptrdiff_t)(okc ? xco[q] : x)];
    }
    sb = acc * rkb[pb];
  }
  float best = -1e30f;
  int bi = 0;
  for (int p = p0; p < p0 + PSLAB; p += 4) {
    // phase 1: issue all 36 tap loads + 4 rk loads (independent, static idx)
    float dv[4][9];
    float rv[4];
#pragma unroll
    for (int u = 0; u < 4; u++) {
      const float* Dp = D + (size_t)(p + u) * NP;   // uniform -> SGPR base
#pragma unroll
      for (int q = 0; q < 9; q++) dv[u][q] = Dp[(ptrdiff_t)xco[q]];
      rv[u] = rkb[p + u];
    }
    // phase 2: weighted sums + in-order compares (boundary p substituted)
#pragma unroll
    for (int u = 0; u < 4; u++) {
      float acc = 0.f;
#pragma unroll
      for (int q = 0; q < 9; q++) acc += w[q] * dv[u][q];
      float s = (p + u == pb) ? sb : acc * rv[u];
      if (s > best) { best = s; bi = p + u; }
    }
  }
  unsigned long long key = ((unsigned long long)sortable_f32(best) << 32) |
                           (unsigned)(~(unsigned)bi);
  atomicMax(&packed[(size_t)b * NP + x], key);
}

// ---------------------------------------------------------------------------
// 11. gather-form overlap-add reassembly, divided by deconv norm (reads nswT [p][c]).
//     Unpacks argmax p from the packed u64 (p = ~lo & 4095).
__global__ __launch_bounds__(256) void reassemble_kernel(const float* __restrict__ nswT,
                                                         const unsigned long long* __restrict__ packed,
                                                         float* __restrict__ reass) {
  int by = blockIdx.x;       // b*NP + y
  int b = by >> 12, y = by & 4095;
  int yi = y >> 6, yj = y & 63;
  int t = threadIdx.x;       // channel
  float acc = 0.f;
#pragma unroll
  for (int oi = 0; oi < 3; oi++)
#pragma unroll
    for (int oj = 0; oj < 3; oj++) {
      int xi = yi + 1 - oi, xj = yj + 1 - oj;
      if ((unsigned)xi < 64u && (unsigned)xj < 64u) {
        unsigned long long v = packed[(size_t)b * NP + xi * 64 + xj];
        int p = (int)((~(unsigned)(v & 0xFFFFFFFFull)) & 4095u);
        int qi = (p >> 6) + oi - 1, qj = (p & 63) + oj - 1;
        if ((unsigned)qi < 64u && (unsigned)qj < 64u)
          acc += nswT[((size_t)b * NP + qi * 64 + qj) * NC + t];
      }
    }
  int cy = (yi == 0 || yi == 63) ? 2 : 3;
  int cx = (yj == 0 || yj == 63) ? 2 : 3;
  reass[((size_t)b * NP + y) * NC + t] = acc / (float)(cy * cx);
}

// ---------------------------------------------------------------------------
// 12. coloring: out[b][c][y] = sum_j sqr_s[b][c][j]*reass[b][y][j] + mean_s[b][c].
//     sqr_s symmetric -> As staged from rows (float4, conflict-free).
__global__ __launch_bounds__(256) void coloring_kernel(const float* __restrict__ sqr_s,
                                                       const float* __restrict__ reass,
                                                       const float* __restrict__ mean,
                                                       float* __restrict__ out) {
  int b = blockIdx.z;
  const float* A = sqr_s + (size_t)b * NC * NC;
  const float* Bm = reass + (size_t)b * NP * NC;
  const float* mu = mean + (size_t)NB * NC + b * NC;
  float* dst = out + (size_t)b * NC * NP;
  int c0 = blockIdx.x * 64, y0 = blockIdx.y * 64;
  __shared__ float As[32][68];   // [j][c], float4 rows
  __shared__ float Bs[32][66];   // [j][y], transposed scalar writes
  int tid = threadIdx.x, tx = tid & 15, ty = tid >> 4;
  float acc[4][4] = {};
  for (int k0 = 0; k0 < NC; k0 += 32) {
    for (int idx = tid; idx < 512; idx += 256) {
      int kk = idx >> 4, r4 = (idx & 15) * 4;   // A symmetric: row k, cols c
      *(float4*)&As[kk][r4] = *(const float4*)&A[(size_t)(k0 + kk) * NC + c0 + r4];
    }
    for (int idx = tid; idx < 2048; idx += 256) {
      int r = idx >> 5, kk = idx & 31;
      Bs[kk][r] = Bm[(size_t)(y0 + r) * NC + k0 + kk];
    }
    __syncthreads();
#pragma unroll
    for (int kk = 0; kk < 32; kk++) {
      float4 av = *(const float4*)&As[kk][ty * 4];
      float a[4] = {av.x, av.y, av.z, av.w};
      float bb[4];
      *(float2*)&bb[0] = *(const float2*)&Bs[kk][tx * 4];
      *(float2*)&bb[2] = *(const float2*)&Bs[kk][tx * 4 + 2];
#pragma unroll
      for (int i = 0; i < 4; i++)
#pragma unroll
        for (int j = 0; j < 4; j++) acc[i][j] += a[i] * bb[j];
    }
    __syncthreads();
  }
#pragma unroll
  for (int i = 0; i < 4; i++) {
    float m = mu[c0 + ty * 4 + i];
    float4 v = make_float4(acc[i][0] + m, acc[i][1] + m, acc[i][2] + m, acc[i][3] + m);
    *(float4*)&dst[(size_t)(c0 + ty * 4 + i) * NP + y0 + tx * 4] = v;
  }
}

// ---------------------------------------------------------------------------
extern "C" void kernel_launch(void* const* d_in, const int* in_sizes, int n_in,
                              void* d_out, int out_size, void* d_ws, size_t ws_size,
                              hipStream_t stream) {
  (void)in_sizes; (void)n_in; (void)out_size; (void)ws_size;
  const float* content = (const float*)d_in[0];
  const float* style = (const float*)d_in[1];
  float* out = (float*)d_out;

  // workspace carve-up (256B aligned)
  char* w = (char*)d_ws;
  auto alloc = [&](size_t bytes) -> void* {
    void* p = (void*)w;
    w += (bytes + 255) & ~(size_t)255;
    return p;
  };
  float* mean = (float*)alloc(2 * NB * NC * sizeof(float));
  double* pcov = (double*)alloc((size_t)KSPLIT * NM * NC * NC * sizeof(double));  // 32MB
  double* cov = (double*)alloc((size_t)NM * NC * NC * sizeof(double));
  float* Y0 = (float*)alloc((size_t)NM * NC * NC * sizeof(float));   // fp32 NS state
  float* Z0 = (float*)alloc((size_t)NM * NC * NC * sizeof(float));
  float* Y1 = (float*)alloc((size_t)NM * NC * NC * sizeof(float));
  float* Z1 = (float*)alloc((size_t)NM * NC * NC * sizeof(float));
  float* T = (float*)alloc((size_t)NM * NC * NC * sizeof(float));
  double* scaleArr = (double*)alloc(NM * sizeof(double));
  _Float16* Mh = (_Float16*)alloc((size_t)NM * NC * NC * sizeof(_Float16));  // 1MB
  _Float16* Ml = (_Float16*)alloc((size_t)NM * NC * NC * sizeof(_Float16));  // 1MB
  float* sqr_s = (float*)alloc((size_t)NB * NC * NC * sizeof(float));
  float* nswT = (float*)alloc((size_t)NB * NP * NC * sizeof(float));  // [p][c]
  float* ssqp = (float*)alloc((size_t)4 * NB * NP * sizeof(float));   // 4 partial slots
  float* rk = (float*)alloc((size_t)NB * NP * sizeof(float));
  unsigned long long* packed =
      (unsigned long long*)alloc((size_t)NB * NP * sizeof(unsigned long long));  // 128KB
  float* Dbuf = (float*)alloc((size_t)NP * NP * sizeof(float));  // 64MB, multi-overlaid:
  float* reass = Dbuf + (size_t)NB * NP * NC;          // [16MB, 32MB), used after score loop
  // raw fp16 split overlays Dbuf[0,32MB) — dead before dmat first writes Dbuf
  _Float16* Czh = (_Float16*)Dbuf;                       // 16MB: NM*NC*NP fp16 [k][p]
  _Float16* Czl = Czh + (size_t)NM * NC * NP;            // 16MB
  // transposed raw split overlays Dbuf[32MB,64MB) — also dead before dmat
  _Float16* CzhT = Czh + (size_t)2 * NM * NC * NP;       // 16MB: [p][k]
  _Float16* CzlT = CzhT + (size_t)NM * NC * NP;          // 16MB
  // whitened fp16 split arrays overlay pcov (dead after cov_reduce): 4 x 8MB
  _Float16* AhiT = (_Float16*)pcov;
  _Float16* AloT = AhiT + (size_t)NB * NP * NC;
  _Float16* BhiT = AloT + (size_t)NB * NP * NC;
  _Float16* BloT = BhiT + (size_t)NB * NP * NC;

  // 1-2: fused mean + raw split, then MFMA syrk cov
  meansplit_kernel<<<2 * NB * NC, 256, 0, stream>>>(content, style, mean, Czh, Czl);
  cov_mfma_kernel<<<dim3(10, KSPLIT, NM), 256, 0, stream>>>(Czh, Czl, pcov);
  cov_reduce_kernel<<<NM * NC * NC / 256, 256, 0, stream>>>(pcov, cov);

  // 2c: transpose raw split to [p][k] for the MFMA whiten A-operand
  transpose_kernel<<<dim3(NP / 64, NC / 64, NM), 256, 0, stream>>>(Czh, Czl, CzhT, CzlT);

  // 3-4: Newton-Schulz inverse/forward sqrt (fp32, Gershgorin-scaled,
  //      symmetric upper-tri tiles only)
  bound_init_kernel<<<NM, 256, 0, stream>>>(cov, Y0, Z0, scaleArr);
  float *Ya = Y0, *Za = Z0, *Yb = Y1, *Zb = Z1;
  for (int it = 0; it < NS_ITERS; it++) {
    ns_t_kernel<<<dim3(NTILE8, 1, NM), 256, 0, stream>>>(Za, Ya, T);
    ns_upd_kernel<<<dim3(NTILE8, 1, NM * 2), 256, 0, stream>>>(Ya, Za, T, Yb, Zb);
    float* tmp;
    tmp = Ya; Ya = Yb; Yb = tmp;
    tmp = Za; Za = Zb; Zb = tmp;
  }
  finalize_kernel<<<dim3(NM * NC * NC / 256, 2), 256, 0, stream>>>(Ya, Za, scaleArr,
                                                                   Mh, Ml, sqr_s);

  // 6: MFMA whiten both features with fused fp16-split epilogue + style ssq
  whiten_mfma_kernel<<<dim3(NP / 128, NC / 128, NM), 256, 0, stream>>>(
      CzhT, CzlT, Mh, Ml, BhiT, BloT, AhiT, AloT, nswT, ssqp);

  // 7: knorm box from ssq partials
  rknorm_kernel<<<NB * NP / 256, 256, 0, stream>>>(ssqp, rk);

  // 8-9: zero packed argmax keys, then per batch: D = A B^T (MFMA fp16
  //      3-term), score with fused atomicMax argmax
  hipMemsetAsync(packed, 0, (size_t)NB * NP * sizeof(unsigned long long), stream);
  for (int b = 0; b < NB; b++) {
    dmat_kernel<<<dim3(NP / 128, NP / 128), 256, 0, stream>>>(AhiT, AloT, BhiT, BloT, Dbuf, b);
    score_kernel<<<dim3(NP / 256, NSLAB), 256, 0, stream>>>(Dbuf, rk, packed, b);
  }

  // 11: reassembly (gather form) straight from nswT, unpacking argmax keys
  reassemble_kernel<<<NB * NP, 256, 0, stream>>>(nswT, packed, reass);

  // 12: coloring straight into d_out (style_strength == 1.0)
  coloring_kernel<<<dim3(NC / 64, NP / 64, NB), 256, 0, stream>>>(sqr_s, reass, mean, out);
}

// Round 4
// 781.269 us; speedup vs baseline: 1.3555x; 1.0746x over previous
//
#include <hip/hip_runtime.h>
#include <stdint.h>
#include <stddef.h>

// Problem constants
constexpr int NB = 4;      // batch
constexpr int NC = 256;    // channels
constexpr int HW = 64;     // spatial side
constexpr int NP = 4096;   // HW*HW
constexpr int NM = 8;      // matrices for Newton-Schulz: 2 feats x 4 batches
constexpr int NS_ITERS = 7;       // lam_scaled ~0.135 -> residual saturates fp32 eps at 7
constexpr int NSLAB = 128;        // score slabs (combine fused via atomicMax)
constexpr int PSLAB = NP / NSLAB; // 32
constexpr int KSPLIT = 8;         // cov K-split
constexpr int KCHUNK = NP / KSPLIT; // 512
constexpr int NTILE8 = 36;        // upper-tri 32-tiles in 8x8 grid (NS symmetric)

// fp16 Markidis split (bf16 2-split caused argmax flips). Pre-scale by 512
// keeps lo out of fp16-subnormal range; uniform scaling is argmax-invariant
// for D, and is divided back out for cov.
constexpr float SPLIT_SCALE = 512.0f;
constexpr double COV_DESCALE = 1.0 / ((double)SPLIT_SCALE * (double)SPLIT_SCALE);

typedef __attribute__((ext_vector_type(8))) _Float16 h8v;  // 8 fp16 (4 VGPRs)
typedef __attribute__((ext_vector_type(4))) _Float16 h4v;  // 4 fp16 (8B store)
typedef __attribute__((ext_vector_type(4))) float f4v;     // MFMA acc

// async global->LDS, 16B per lane; lds arg must be wave-uniform
#define GLD16(lds, g)                                                        \
  __builtin_amdgcn_global_load_lds(                                          \
      (const __attribute__((address_space(1))) void*)(g),                    \
      (__attribute__((address_space(3))) void*)(lds), 16, 0, 0)

// monotone float -> sortable u32 (finite inputs): order(f) == order(sortable(f))
__device__ inline unsigned sortable_f32(float f) {
  unsigned u = __float_as_uint(f);
  return (u & 0x80000000u) ? ~u : (u | 0x80000000u);
}

// ---------------------------------------------------------------------------
// 1. fused mean + raw fp16 split: (src-mu)*512 -> fp16 hi/lo in [c][p]
__global__ __launch_bounds__(256) void meansplit_kernel(const float* __restrict__ content,
                                                        const float* __restrict__ style,
                                                        float* __restrict__ mean,
                                                        _Float16* __restrict__ Czh,
                                                        _Float16* __restrict__ Czl) {
  int id = blockIdx.x;              // [0, 2*NB*NC) == m*NC + c
  int feat = id / (NB * NC);
  int bc = id % (NB * NC);
  const float* src = (feat ? style : content) + (size_t)bc * NP;
  int tid = threadIdx.x;
  float s = 0.f;
  for (int i = tid; i < NP; i += 256) s += src[i];
  __shared__ float red[256];
  red[tid] = s;
  __syncthreads();
  for (int st = 128; st > 0; st >>= 1) {
    if (tid < st) red[tid] += red[tid + st];
    __syncthreads();
  }
  float mu = red[0] * (1.0f / NP);
  if (tid == 0) mean[id] = mu;
  _Float16* oh = Czh + (size_t)id * NP;
  _Float16* ol = Czl + (size_t)id * NP;
  for (int f4 = tid; f4 < NP / 4; f4 += 256) {
    float4 v = *(const float4*)&src[f4 * 4];
    float vv[4] = {v.x, v.y, v.z, v.w};
    h4v h, l;
#pragma unroll
    for (int q = 0; q < 4; q++) {
      float sv = (vv[q] - mu) * SPLIT_SCALE;
      _Float16 hh = (_Float16)sv;
      h[q] = hh;
      l[q] = (_Float16)(sv - (float)hh);
    }
    *(h4v*)&oh[f4 * 4] = h;
    *(h4v*)&ol[f4 * 4] = l;
  }
}

// ---------------------------------------------------------------------------
// 2. MFMA syrk cov: 64x64 upper-tri tiles, 4-term fp16 split, per-32-k fp64 fold
__global__ __launch_bounds__(256) void cov_mfma_kernel(const _Float16* __restrict__ Czh,
                                                       const _Float16* __restrict__ Czl,
                                                       double* __restrict__ pcov) {
  __shared__ _Float16 sAh[64 * 32], sAl[64 * 32], sBh[64 * 32], sBl[64 * 32];
  int m = blockIdx.z;
  int t = blockIdx.x, ti = 0, rem = t;
  while (rem >= 4 - ti) { rem -= 4 - ti; ti++; }
  int tj = ti + rem;
  int i0 = ti * 64, j0 = tj * 64;
  const _Float16* Ah = Czh + ((size_t)m * NC + i0) * NP;
  const _Float16* Al = Czl + ((size_t)m * NC + i0) * NP;
  const _Float16* Bh = Czh + ((size_t)m * NC + j0) * NP;
  const _Float16* Bl = Czl + ((size_t)m * NC + j0) * NP;
  int k0base = blockIdx.y * KCHUNK;
  int tid = threadIdx.x, lane = tid & 63;
  int mm = lane & 15, quad = lane >> 4;
  int w = tid >> 6, qr = w & 1, qc = w >> 1;
  double dacc[2][2][4] = {};
  for (int step = 0; step < KCHUNK / 32; step++) {
    int k0 = k0base + step * 32;
    __syncthreads();
    {
      int row = tid >> 2, koff = (tid & 3) * 8;
      int sbase = (tid & ~63) * 8;   // wave-uniform
      GLD16(&sAh[sbase], Ah + (size_t)row * NP + k0 + koff);
      GLD16(&sAl[sbase], Al + (size_t)row * NP + k0 + koff);
      GLD16(&sBh[sbase], Bh + (size_t)row * NP + k0 + koff);
      GLD16(&sBl[sbase], Bl + (size_t)row * NP + k0 + koff);
    }
    __syncthreads();   // drains vmcnt per barrier semantics
    h8v afh[2], afl[2], bfh[2], bfl[2];
#pragma unroll
    for (int tt = 0; tt < 2; tt++) {
      int ra = (qr * 32 + tt * 16 + mm) * 32 + quad * 8;
      afh[tt] = *(const h8v*)&sAh[ra];
      afl[tt] = *(const h8v*)&sAl[ra];
      int rb = (qc * 32 + tt * 16 + mm) * 32 + quad * 8;
      bfh[tt] = *(const h8v*)&sBh[rb];
      bfl[tt] = *(const h8v*)&sBl[rb];
    }
    f4v acc[2][2] = {};
#pragma unroll
    for (int tr = 0; tr < 2; tr++)
#pragma unroll
      for (int tc = 0; tc < 2; tc++) {
        acc[tr][tc] = __builtin_amdgcn_mfma_f32_16x16x32_f16(afh[tr], bfh[tc], acc[tr][tc], 0, 0, 0);
        acc[tr][tc] = __builtin_amdgcn_mfma_f32_16x16x32_f16(afh[tr], bfl[tc], acc[tr][tc], 0, 0, 0);
        acc[tr][tc] = __builtin_amdgcn_mfma_f32_16x16x32_f16(afl[tr], bfh[tc], acc[tr][tc], 0, 0, 0);
        acc[tr][tc] = __builtin_amdgcn_mfma_f32_16x16x32_f16(afl[tr], bfl[tc], acc[tr][tc], 0, 0, 0);
      }
#pragma unroll
    for (int tr = 0; tr < 2; tr++)
#pragma unroll
      for (int tc = 0; tc < 2; tc++)
#pragma unroll
        for (int r = 0; r < 4; r++) dacc[tr][tc][r] += (double)acc[tr][tc][r];
  }
  double* dst = pcov + ((size_t)blockIdx.y * NM + m) * NC * NC;
  // C/D layout: col = lane&15, row = quad*4 + reg  [verified mapping]
#pragma unroll
  for (int tr = 0; tr < 2; tr++)
#pragma unroll
    for (int tc = 0; tc < 2; tc++)
#pragma unroll
      for (int r = 0; r < 4; r++) {
        int row = i0 + qr * 32 + tr * 16 + quad * 4 + r;
        int col = j0 + qc * 32 + tc * 16 + mm;
        dst[(size_t)row * NC + col] = dacc[tr][tc][r];
      }
}

// 2b. sum K-split partials; mirror lower triangle from upper tiles; descale
__global__ __launch_bounds__(256) void cov_reduce_kernel(const double* __restrict__ pcov,
                                                         double* __restrict__ cov) {
  size_t idx = (size_t)blockIdx.x * 256 + threadIdx.x;  // [0, NM*NC*NC)
  int m = (int)(idx >> 16);
  int ij = (int)(idx & 65535);
  int i = ij >> 8, j = ij & 255;
  int src = ((i >> 6) <= (j >> 6)) ? ij : ((j << 8) | i);
  double s = 0;
  for (int k = 0; k < KSPLIT; k++)
    s += pcov[((size_t)k * NM + m) * 65536 + src];
  cov[idx] = s * COV_DESCALE;
}

// ---------------------------------------------------------------------------
// 2c. fp16 tile transpose: Czh/Czl [m][k][p] -> CzhT/CzlT [m][p][k], so the
//     MFMA whiten can read k-contiguous A fragments. 64x64 tiles, LDS pad 72
//     (144B stride: 8B-aligned, 2-way bank alias = free).
__global__ __launch_bounds__(256) void transpose_kernel(const _Float16* __restrict__ Czh,
                                                        const _Float16* __restrict__ Czl,
                                                        _Float16* __restrict__ CzhT,
                                                        _Float16* __restrict__ CzlT) {
  __shared__ unsigned short th[64][72], tl[64][72];
  int m = blockIdx.z;
  int p0 = blockIdx.x * 64, k0 = blockIdx.y * 64;
  int tid = threadIdx.x;
  const unsigned short* src_h = (const unsigned short*)(Czh + (size_t)m * NC * NP);
  const unsigned short* src_l = (const unsigned short*)(Czl + (size_t)m * NC * NP);
#pragma unroll
  for (int j = 0; j < 4; j++) {
    int e = j * 1024 + tid * 4;
    int kk = e >> 6, pp = e & 63;
    ushort4 vh = *(const ushort4*)&src_h[(size_t)(k0 + kk) * NP + p0 + pp];
    ushort4 vl = *(const ushort4*)&src_l[(size_t)(k0 + kk) * NP + p0 + pp];
    *(ushort4*)&th[kk][pp] = vh;
    *(ushort4*)&tl[kk][pp] = vl;
  }
  __syncthreads();
  unsigned short* dst_h = (unsigned short*)(CzhT + (size_t)m * NP * NC);
  unsigned short* dst_l = (unsigned short*)(CzlT + (size_t)m * NP * NC);
#pragma unroll
  for (int j = 0; j < 4; j++) {
    int e = j * 1024 + tid * 4;
    int pp = e >> 6, kk = e & 63;
    ushort4 vh, vl;
    vh.x = th[kk][pp];     vh.y = th[kk + 1][pp];
    vh.z = th[kk + 2][pp]; vh.w = th[kk + 3][pp];
    vl.x = tl[kk][pp];     vl.y = tl[kk + 1][pp];
    vl.z = tl[kk + 2][pp]; vl.w = tl[kk + 3][pp];
    *(ushort4*)&dst_h[(size_t)(p0 + pp) * NC + k0 + kk] = vh;
    *(ushort4*)&dst_l[(size_t)(p0 + pp) * NC + k0 + kk] = vl;
  }
}

// ---------------------------------------------------------------------------
// 3a. Gershgorin bound, parallel: cov is exactly symmetric (cov_reduce
//     mirrors), so col |sums| == row |sums|; rows are contiguous -> one wave
//     per row, coalesced reads, 64-lane shuffle reduce. (Round-3 post-mortem:
//     old single kernel ran 8 blocks -> 0.3% occupancy, 46 us latency-bound.)
__global__ __launch_bounds__(256) void bound_rowsum_kernel(const double* __restrict__ cov,
                                                           double* __restrict__ rowsum) {
  int m = blockIdx.y;
  int row = blockIdx.x * 4 + (threadIdx.x >> 6);
  int lane = threadIdx.x & 63;
  const double* A = cov + ((size_t)m * NC + row) * NC;
  double s = 0;
#pragma unroll
  for (int k = 0; k < 4; k++) s += fabs(A[lane + k * 64]);
#pragma unroll
  for (int off = 32; off > 0; off >>= 1) s += __shfl_down(s, off);
  if (lane == 0) rowsum[m * NC + row] = s;
}

// 3b. scale = 1/max(rowsum) (each block re-reduces the 256 rowsums, L2-hit,
//     avoiding a third dependent launch); init Y = s*A (fp32), Z = I.
__global__ __launch_bounds__(256) void bound_init2_kernel(const double* __restrict__ cov,
                                                          const double* __restrict__ rowsum,
                                                          float* __restrict__ Y,
                                                          float* __restrict__ Z,
                                                          double* __restrict__ scaleArr) {
  int m = blockIdx.y;
  int tid = threadIdx.x;
  __shared__ double red[256];
  red[tid] = rowsum[m * NC + tid];
  __syncthreads();
  for (int st = 128; st > 0; st >>= 1) {
    if (tid < st) red[tid] = fmax(red[tid], red[tid + st]);
    __syncthreads();
  }
  double scale = 1.0 / red[0];     // lam_max <= max abs row sum (rigorous upper bound)
  if (blockIdx.x == 0 && tid == 0) scaleArr[m] = scale;
  const double* A = cov + (size_t)m * NC * NC;
  float* Ym = Y + (size_t)m * NC * NC;
  float* Zm = Z + (size_t)m * NC * NC;
  int base = blockIdx.x * 2048;
#pragma unroll
  for (int k = 0; k < 8; k++) {
    int idx = base + k * 256 + tid;
    Ym[idx] = (float)(A[idx] * scale);
    Zm[idx] = ((idx >> 8) == (idx & 255)) ? 1.0f : 0.0f;
  }
}

// ---------------------------------------------------------------------------
// NS iterates are polynomials in symmetric A -> Y, Z, T, Y*T, T*Z all
// symmetric. Upper-tri 32x32 tiles only, mirror-write lower. fp32.

// 4a. T = Z * Y (fp32, upper-tri 32x32 tiles, 2x2 micro, mirrored writes)
__global__ __launch_bounds__(256) void ns_t_kernel(const float* __restrict__ Zin,
                                                   const float* __restrict__ Yin,
                                                   float* __restrict__ T) {
  int m = blockIdx.z;
  const float* Am = Zin + (size_t)m * NC * NC;
  const float* Bm = Yin + (size_t)m * NC * NC;
  float* Tm = T + (size_t)m * NC * NC;
  __shared__ float As[32][33];
  __shared__ float Bs[32][33];
  int tid = threadIdx.x, tx = tid & 15, ty = tid >> 4;
  int t = blockIdx.x, ti = 0, rem = t;     // unrank upper-tri tile (8x8 grid)
  while (rem >= 8 - ti) { rem -= 8 - ti; ti++; }
  int tj = ti + rem;
  int i0 = ti * 32, j0 = tj * 32;
  float a00 = 0, a01 = 0, a10 = 0, a11 = 0;
  for (int k0 = 0; k0 < NC; k0 += 32) {
    for (int idx = tid; idx < 1024; idx += 256) {
      int r = idx >> 5, cc = idx & 31;
      As[r][cc] = Am[(size_t)(i0 + r) * NC + k0 + cc];
      Bs[r][cc] = Bm[(size_t)(k0 + r) * NC + j0 + cc];
    }
    __syncthreads();
#pragma unroll
    for (int kk = 0; kk < 32; kk++) {
      float x0 = As[ty * 2][kk], x1 = As[ty * 2 + 1][kk];
      float y0 = Bs[kk][tx * 2], y1 = Bs[kk][tx * 2 + 1];
      a00 += x0 * y0; a01 += x0 * y1; a10 += x1 * y0; a11 += x1 * y1;
    }
    __syncthreads();
  }
  Tm[(size_t)(i0 + ty * 2) * NC + j0 + tx * 2] = a00;
  Tm[(size_t)(i0 + ty * 2) * NC + j0 + tx * 2 + 1] = a01;
  Tm[(size_t)(i0 + ty * 2 + 1) * NC + j0 + tx * 2] = a10;
  Tm[(size_t)(i0 + ty * 2 + 1) * NC + j0 + tx * 2 + 1] = a11;
  if (ti != tj) {   // mirror tile, coalesced via LDS transpose (reuse As)
    As[ty * 2][tx * 2] = a00;
    As[ty * 2][tx * 2 + 1] = a01;
    As[ty * 2 + 1][tx * 2] = a10;
    As[ty * 2 + 1][tx * 2 + 1] = a11;
    __syncthreads();
    for (int idx = tid; idx < 1024; idx += 256) {
      int r = idx >> 5, cc = idx & 31;
      Tm[(size_t)(j0 + r) * NC + i0 + cc] = As[cc][r];
    }
  }
}

// 4b. Yout = 1.5*Yin - 0.5*Yin*T ; Zout = 1.5*Zin - 0.5*T*Zin  (fp32)
__global__ __launch_bounds__(256) void ns_upd_kernel(const float* __restrict__ Yin,
                                                     const float* __restrict__ Zin,
                                                     const float* __restrict__ T,
                                                     float* __restrict__ Yout,
                                                     float* __restrict__ Zout) {
  int z = blockIdx.z;
  int m = z & 7, which = z >> 3;
  size_t off = (size_t)m * NC * NC;
  const float* Am = which == 0 ? (Yin + off) : (T + off);
  const float* Bm = which == 0 ? (T + off) : (Zin + off);
  const float* Sm = which == 0 ? (Yin + off) : (Zin + off);
  float* Om = which == 0 ? (Yout + off) : (Zout + off);
  __shared__ float As[32][33];
  __shared__ float Bs[32][33];
  int tid = threadIdx.x, tx = tid & 15, ty = tid >> 4;
  int t = blockIdx.x, ti = 0, rem = t;     // unrank upper-tri tile (8x8 grid)
  while (rem >= 8 - ti) { rem -= 8 - ti; ti++; }
  int tj = ti + rem;
  int i0 = ti * 32, j0 = tj * 32;
  float a00 = 0, a01 = 0, a10 = 0, a11 = 0;
  for (int k0 = 0; k0 < NC; k0 += 32) {
    for (int idx = tid; idx < 1024; idx += 256) {
      int r = idx >> 5, cc = idx & 31;
      As[r][cc] = Am[(size_t)(i0 + r) * NC + k0 + cc];
      Bs[r][cc] = Bm[(size_t)(k0 + r) * NC + j0 + cc];
    }
    __syncthreads();
#pragma unroll
    for (int kk = 0; kk < 32; kk++) {
      float x0 = As[ty * 2][kk], x1 = As[ty * 2 + 1][kk];
      float y0 = Bs[kk][tx * 2], y1 = Bs[kk][tx * 2 + 1];
      a00 += x0 * y0; a01 += x0 * y1; a10 += x1 * y0; a11 += x1 * y1;
    }
    __syncthreads();
  }
  int r0 = i0 + ty * 2, c0 = j0 + tx * 2;
  float o00 = 1.5f * Sm[(size_t)r0 * NC + c0] - 0.5f * a00;
  float o01 = 1.5f * Sm[(size_t)r0 * NC + c0 + 1] - 0.5f * a01;
  float o10 = 1.5f * Sm[(size_t)(r0 + 1) * NC + c0] - 0.5f * a10;
  float o11 = 1.5f * Sm[(size_t)(r0 + 1) * NC + c0 + 1] - 0.5f * a11;
  Om[(size_t)r0 * NC + c0] = o00;
  Om[(size_t)r0 * NC + c0 + 1] = o01;
  Om[(size_t)(r0 + 1) * NC + c0] = o10;
  Om[(size_t)(r0 + 1) * NC + c0 + 1] = o11;
  if (ti != tj) {   // mirror tile via LDS transpose (reuse As)
    As[ty * 2][tx * 2] = o00;
    As[ty * 2][tx * 2 + 1] = o01;
    As[ty * 2 + 1][tx * 2] = o10;
    As[ty * 2 + 1][tx * 2 + 1] = o11;
    __syncthreads();
    for (int idx = tid; idx < 1024; idx += 256) {
      int r = idx >> 5, cc = idx & 31;
      Om[(size_t)(j0 + r) * NC + i0 + cc] = As[cc][r];
    }
  }
}

// ---------------------------------------------------------------------------
// 5. finalize: Mh/Ml[m] = fp16-split( Z[m]*sqrt(scale[m]) * 512 )  (whiten B
//    operand, k-contiguous rows; Z symmetric so row-major serves both roles);
//    sqr_s[b] = Y_s / sqrt(scale) in fp32 for coloring.
__global__ __launch_bounds__(256) void finalize_kernel(const float* __restrict__ Yf,
                                                       const float* __restrict__ Zf,
                                                       const double* __restrict__ scaleArr,
                                                       _Float16* __restrict__ Mh,
                                                       _Float16* __restrict__ Ml,
                                                       float* __restrict__ sqr_s) {
  int which = blockIdx.y;
  int idx = blockIdx.x * 256 + threadIdx.x;   // [0, NM*NC*NC)
  int m = idx >> 16;
  int ij = idx & 65535;
  if (which == 0) {
    double s = sqrt(scaleArr[m]);
    float v = (float)((double)Zf[idx] * s) * SPLIT_SCALE;
    _Float16 h = (_Float16)v;
    Mh[idx] = h;
    Ml[idx] = (_Float16)(v - (float)h);
  } else {
    if (m >= NB) return;
    double s = sqrt(scaleArr[4 + m]);
    sqr_s[idx] = (float)((double)Yf[(size_t)(4 + m) * 65536 + ij] / s);
  }
}

// ---------------------------------------------------------------------------
// 6. MFMA whiten (replaces fp32 whiten + split pass):
//    out[p][c] = sum_k CzT[p][k] * M[k][c], 3-term fp16 split, 128x128 tile,
//    4 waves each 64x64, BK=32, global_load_lds staging (dmat structure).
//    acc = whitened * 512^2. Epilogue fuses the old split_kernel:
//      hi/lo = split(acc/512)  -> Ahi/Alo (style) or Bhi/Blo (content)
//      nswT fp32 + ssq partials (style only; deterministic 4-slot partials).
__global__ __launch_bounds__(256) void whiten_mfma_kernel(const _Float16* __restrict__ CzhT,
                                                          const _Float16* __restrict__ CzlT,
                                                          const _Float16* __restrict__ Mh,
                                                          const _Float16* __restrict__ Ml,
                                                          _Float16* __restrict__ BhiT,
                                                          _Float16* __restrict__ BloT,
                                                          _Float16* __restrict__ AhiT,
                                                          _Float16* __restrict__ AloT,
                                                          float* __restrict__ nswT,
                                                          float* __restrict__ ssqp) {
  __shared__ _Float16 sAh[128 * 32], sAl[128 * 32], sBh[128 * 32], sBl[128 * 32];
  int m = blockIdx.z;
  const _Float16* Ah = CzhT + (size_t)m * NP * NC;
  const _Float16* Al = CzlT + (size_t)m * NP * NC;
  const _Float16* Bh = Mh + (size_t)m * NC * NC;
  const _Float16* Bl = Ml + (size_t)m * NC * NC;
  int p0 = blockIdx.x * 128, c0 = blockIdx.y * 128;
  int tid = threadIdx.x, lane = tid & 63;
  int mm = lane & 15, quad = lane >> 4;
  int w = tid >> 6, qr = w & 1, qc = w >> 1;
  f4v acc[4][4] = {};
  for (int step = 0; step < NC / 32; step++) {
    int k0 = step * 32;
    __syncthreads();
#pragma unroll
    for (int i = 0; i < 2; i++) {
      int seg = i * 256 + tid;
      int row = seg >> 2, koff = (seg & 3) * 8;
      int sbase = (i * 256 + (tid & ~63)) * 8;   // wave-uniform
      GLD16(&sAh[sbase], Ah + (size_t)(p0 + row) * NC + k0 + koff);
      GLD16(&sAl[sbase], Al + (size_t)(p0 + row) * NC + k0 + koff);
      GLD16(&sBh[sbase], Bh + (size_t)(c0 + row) * NC + k0 + koff);
      GLD16(&sBl[sbase], Bl + (size_t)(c0 + row) * NC + k0 + koff);
    }
    __syncthreads();   // drains vmcnt (global_load_lds) per barrier semantics
    h8v afh[4], afl[4], bfh[4], bfl[4];
#pragma unroll
    for (int t = 0; t < 4; t++) {
      int ra = (qr * 64 + t * 16 + mm) * 32 + quad * 8;
      afh[t] = *(const h8v*)&sAh[ra];
      afl[t] = *(const h8v*)&sAl[ra];
      int rb = (qc * 64 + t * 16 + mm) * 32 + quad * 8;
      bfh[t] = *(const h8v*)&sBh[rb];
      bfl[t] = *(const h8v*)&sBl[rb];
    }
#pragma unroll
    for (int tr = 0; tr < 4; tr++)
#pragma unroll
      for (int tc = 0; tc < 4; tc++) {
        acc[tr][tc] = __builtin_amdgcn_mfma_f32_16x16x32_f16(afh[tr], bfh[tc], acc[tr][tc], 0, 0, 0);
        acc[tr][tc] = __builtin_amdgcn_mfma_f32_16x16x32_f16(afh[tr], bfl[tc], acc[tr][tc], 0, 0, 0);
        acc[tr][tc] = __builtin_amdgcn_mfma_f32_16x16x32_f16(afl[tr], bfh[tc], acc[tr][tc], 0, 0, 0);
      }
  }
  int feat = m >> 2, b = m & 3;
  _Float16* oh = (feat ? AhiT : BhiT) + (size_t)b * NP * NC;
  _Float16* ol = (feat ? AloT : BloT) + (size_t)b * NP * NC;
  float* nsw = nswT + (size_t)b * NP * NC;
  const float DSPL = 1.0f / SPLIT_SCALE;          // acc*DSPL = whitened*512
  const float DESC = DSPL * DSPL;                 // acc*DESC = whitened
  // C/D layout: col = lane&15, row = quad*4 + reg  [verified mapping]
#pragma unroll
  for (int tr = 0; tr < 4; tr++)
#pragma unroll
    for (int r = 0; r < 4; r++) {
      int p = p0 + qr * 64 + tr * 16 + quad * 4 + r;
      float ps = 0.f;
#pragma unroll
      for (int tc = 0; tc < 4; tc++) {
        int c = c0 + qc * 64 + tc * 16 + mm;
        float a = acc[tr][tc][r];
        float sv = a * DSPL;
        _Float16 hh = (_Float16)sv;
        size_t o = (size_t)p * NC + c;
        oh[o] = hh;
        ol[o] = (_Float16)(sv - (float)hh);
        if (feat) {
          float v = a * DESC;
          nsw[o] = v;
          ps += v * v;
        }
      }
      if (feat) {   // 16-lane (mm) reduce -> one deterministic partial per p
        ps += __shfl_xor(ps, 1);
        ps += __shfl_xor(ps, 2);
        ps += __shfl_xor(ps, 4);
        ps += __shfl_xor(ps, 8);
        if (mm == 0)
          ssqp[((size_t)(blockIdx.y * 2 + qc) * NB + b) * NP + p] = ps;
      }
    }
}

// ---------------------------------------------------------------------------
// 7. knorm box from the 4 deterministic ssq partials per (b,p)
__global__ __launch_bounds__(256) void rknorm_kernel(const float* __restrict__ ssqp,
                                                     float* __restrict__ rk) {
  int idx = blockIdx.x * 256 + threadIdx.x;
  int b = idx >> 12, p = idx & 4095;
  int pi = p >> 6, pj = p & 63;
  float s = 0.f;
#pragma unroll
  for (int d = -1; d <= 1; d++)
#pragma unroll
    for (int e = -1; e <= 1; e++) {
      if ((unsigned)(pi + d) < 64u && (unsigned)(pj + e) < 64u) {
        int q = b * NP + (pi + d) * 64 + pj + e;
#pragma unroll
        for (int sl = 0; sl < 4; sl++) s += ssqp[(size_t)sl * NB * NP + q];
      }
    }
  rk[idx] = 1.0f / sqrtf(s);
}

// ---------------------------------------------------------------------------
// 8. MFMA: D[p][x] = sum_c A[p][c]*B[x][c] via 3-term fp16 split (hh, hl, lh).
//    128x128 tile/block, 4 waves each 64x64 (4x4 of mfma_f32_16x16x32_f16),
//    BK=32, global_load_lds 16B staging.
__global__ __launch_bounds__(256) void dmat_kernel(const _Float16* __restrict__ AhiT,
                                                   const _Float16* __restrict__ AloT,
                                                   const _Float16* __restrict__ BhiT,
                                                   const _Float16* __restrict__ BloT,
                                                   float* __restrict__ D, int b) {
  __shared__ _Float16 sAh[128 * 32], sAl[128 * 32], sBh[128 * 32], sBl[128 * 32];
  const _Float16* Ah = AhiT + (size_t)b * NP * NC;
  const _Float16* Al = AloT + (size_t)b * NP * NC;
  const _Float16* Bh = BhiT + (size_t)b * NP * NC;
  const _Float16* Bl = BloT + (size_t)b * NP * NC;
  int p0 = blockIdx.x * 128, x0 = blockIdx.y * 128;
  int tid = threadIdx.x, lane = tid & 63;
  int m = lane & 15, quad = lane >> 4;
  int w = tid >> 6, qr = w & 1, qc = w >> 1;
  f4v acc[4][4] = {};
  for (int step = 0; step < NC / 32; step++) {
    int c0 = step * 32;
    __syncthreads();
#pragma unroll
    for (int i = 0; i < 2; i++) {
      int seg = i * 256 + tid;
      int row = seg >> 2, koff = (seg & 3) * 8;
      int sbase = (i * 256 + (tid & ~63)) * 8;   // wave-uniform
      GLD16(&sAh[sbase], Ah + (size_t)(p0 + row) * NC + c0 + koff);
      GLD16(&sAl[sbase], Al + (size_t)(p0 + row) * NC + c0 + koff);
      GLD16(&sBh[sbase], Bh + (size_t)(x0 + row) * NC + c0 + koff);
      GLD16(&sBl[sbase], Bl + (size_t)(x0 + row) * NC + c0 + koff);
    }
    __syncthreads();   // drains vmcnt (global_load_lds) per barrier semantics
    h8v afh[4], afl[4], bfh[4], bfl[4];
#pragma unroll
    for (int t = 0; t < 4; t++) {
      int ra = (qr * 64 + t * 16 + m) * 32 + quad * 8;
      afh[t] = *(const h8v*)&sAh[ra];
      afl[t] = *(const h8v*)&sAl[ra];
      int rb = (qc * 64 + t * 16 + m) * 32 + quad * 8;
      bfh[t] = *(const h8v*)&sBh[rb];
      bfl[t] = *(const h8v*)&sBl[rb];
    }
#pragma unroll
    for (int tr = 0; tr < 4; tr++)
#pragma unroll
      for (int tc = 0; tc < 4; tc++) {
        acc[tr][tc] = __builtin_amdgcn_mfma_f32_16x16x32_f16(afh[tr], bfh[tc], acc[tr][tc], 0, 0, 0);
        acc[tr][tc] = __builtin_amdgcn_mfma_f32_16x16x32_f16(afh[tr], bfl[tc], acc[tr][tc], 0, 0, 0);
        acc[tr][tc] = __builtin_amdgcn_mfma_f32_16x16x32_f16(afl[tr], bfh[tc], acc[tr][tc], 0, 0, 0);
      }
  }
  // C/D layout: col = lane&15, row = quad*4 + reg  [verified mapping]
#pragma unroll
  for (int tr = 0; tr < 4; tr++)
#pragma unroll
    for (int tc = 0; tc < 4; tc++)
#pragma unroll
      for (int r = 0; r < 4; r++) {
        int row = p0 + qr * 64 + tr * 16 + quad * 4 + r;
        int col = x0 + qc * 64 + tc * 16 + m;
        D[(size_t)row * NP + col] = acc[tr][tc][r];
      }
}

// ---------------------------------------------------------------------------
// 9. score: shifted-sum + slab-local argmax, cross-slab reduction via packed
//    u64 atomicMax: key = (sortable(score)<<32) | ~p (first-max tie rule).
//    Flat-index identity: D[p+off][x+off] = Dflat[p*NP + x + off*(NP+1)] ->
//    taps at constant flat offsets. Round-2 post-mortem: serial per-p loads
//    were latency-bound (VALUBusy 14%, all idle). Fix: batch 4 p's, issue all
//    36 tap loads into registers (static indices) BEFORE the FMA/compare
//    chain -> 36-wide MLP. The one boundary-p per slab (pj==0|63) gets its
//    corrected score precomputed and substituted at compare time; compares
//    run in increasing p order -> bit-identical argmax.
__global__ __launch_bounds__(256) void score_kernel(const float* __restrict__ D,
                                                    const float* __restrict__ rk,
                                                    unsigned long long* __restrict__ packed,
                                                    int b) {
  int x = blockIdx.x * 256 + threadIdx.x;
  int slab = blockIdx.y;
  int xi = x >> 6, xj = x & 63;
  int p0 = slab * PSLAB;
  int pi = p0 >> 6;                 // constant across the slab
  const float* rkb = rk + (size_t)b * NP;
  float w[9];
  int xco[9];                       // x + flat tap offset (loop-invariant VGPRs)
#pragma unroll
  for (int q = 0; q < 9; q++) {
    int d = q / 3 - 1, e = q % 3 - 1;
    bool ok = ((unsigned)(xi + d) < 64u) && ((unsigned)(xj + e) < 64u) &&
              ((unsigned)(pi + d) < 64u);
    w[q] = ok ? 1.0f : 0.0f;
    xco[q] = x + (ok ? (d * 64 + e) * (NP + 1) : 0);
  }
  // boundary p of this slab (exactly one: pj==0 for even slabs, 63 for odd);
  // compute its corrected score up front (col-boundary taps masked).
  int pb = (p0 & 63) ? (p0 + PSLAB - 1) : p0;
  float sb;
  {
    int pj = pb & 63;
    const float* Dp = D + (size_t)pb * NP;
    float acc = 0.f;
#pragma unroll
    for (int q = 0; q < 9; q++) {
      int e = q % 3 - 1;
      bool okc = (unsigned)(pj + e) < 64u;
      float wq = okc ? w[q] : 0.f;
      acc += wq * Dp[(ptrdiff_t)(okc ? xco[q] : x)];
    }
    sb = acc * rkb[pb];
  }
  float best = -1e30f;
  int bi = 0;
  for (int p = p0; p < p0 + PSLAB; p += 4) {
    // phase 1: issue all 36 tap loads + 4 rk loads (independent, static idx)
    float dv[4][9];
    float rv[4];
#pragma unroll
    for (int u = 0; u < 4; u++) {
      const float* Dp = D + (size_t)(p + u) * NP;   // uniform -> SGPR base
#pragma unroll
      for (int q = 0; q < 9; q++) dv[u][q] = Dp[(ptrdiff_t)xco[q]];
      rv[u] = rkb[p + u];
    }
    // phase 2: weighted sums + in-order compares (boundary p substituted)
#pragma unroll
    for (int u = 0; u < 4; u++) {
      float acc = 0.f;
#pragma unroll
      for (int q = 0; q < 9; q++) acc += w[q] * dv[u][q];
      float s = (p + u == pb) ? sb : acc * rv[u];
      if (s > best) { best = s; bi = p + u; }
    }
  }
  unsigned long long key = ((unsigned long long)sortable_f32(best) << 32) |
                           (unsigned)(~(unsigned)bi);
  atomicMax(&packed[(size_t)b * NP + x], key);
}

// ---------------------------------------------------------------------------
// 11. gather-form overlap-add reassembly, divided by deconv norm (reads nswT [p][c]).
//     Unpacks argmax p from the packed u64 (p = ~lo & 4095).
__global__ __launch_bounds__(256) void reassemble_kernel(const float* __restrict__ nswT,
                                                         const unsigned long long* __restrict__ packed,
                                                         float* __restrict__ reass) {
  int by = blockIdx.x;       // b*NP + y
  int b = by >> 12, y = by & 4095;
  int yi = y >> 6, yj = y & 63;
  int t = threadIdx.x;       // channel
  float acc = 0.f;
#pragma unroll
  for (int oi = 0; oi < 3; oi++)
#pragma unroll
    for (int oj = 0; oj < 3; oj++) {
      int xi = yi + 1 - oi, xj = yj + 1 - oj;
      if ((unsigned)xi < 64u && (unsigned)xj < 64u) {
        unsigned long long v = packed[(size_t)b * NP + xi * 64 + xj];
        int p = (int)((~(unsigned)(v & 0xFFFFFFFFull)) & 4095u);
        int qi = (p >> 6) + oi - 1, qj = (p & 63) + oj - 1;
        if ((unsigned)qi < 64u && (unsigned)qj < 64u)
          acc += nswT[((size_t)b * NP + qi * 64 + qj) * NC + t];
      }
    }
  int cy = (yi == 0 || yi == 63) ? 2 : 3;
  int cx = (yj == 0 || yj == 63) ? 2 : 3;
  reass[((size_t)b * NP + y) * NC + t] = acc / (float)(cy * cx);
}

// ---------------------------------------------------------------------------
// 12. coloring: out[b][c][y] = sum_j sqr_s[b][c][j]*reass[b][y][j] + mean_s[b][c].
//     sqr_s symmetric -> As staged from rows (float4, conflict-free).
__global__ __launch_bounds__(256) void coloring_kernel(const float* __restrict__ sqr_s,
                                                       const float* __restrict__ reass,
                                                       const float* __restrict__ mean,
                                                       float* __restrict__ out) {
  int b = blockIdx.z;
  const float* A = sqr_s + (size_t)b * NC * NC;
  const float* Bm = reass + (size_t)b * NP * NC;
  const float* mu = mean + (size_t)NB * NC + b * NC;
  float* dst = out + (size_t)b * NC * NP;
  int c0 = blockIdx.x * 64, y0 = blockIdx.y * 64;
  __shared__ float As[32][68];   // [j][c], float4 rows
  __shared__ float Bs[32][66];   // [j][y], transposed scalar writes
  int tid = threadIdx.x, tx = tid & 15, ty = tid >> 4;
  float acc[4][4] = {};
  for (int k0 = 0; k0 < NC; k0 += 32) {
    for (int idx = tid; idx < 512; idx += 256) {
      int kk = idx >> 4, r4 = (idx & 15) * 4;   // A symmetric: row k, cols c
      *(float4*)&As[kk][r4] = *(const float4*)&A[(size_t)(k0 + kk) * NC + c0 + r4];
    }
    for (int idx = tid; idx < 2048; idx += 256) {
      int r = idx >> 5, kk = idx & 31;
      Bs[kk][r] = Bm[(size_t)(y0 + r) * NC + k0 + kk];
    }
    __syncthreads();
#pragma unroll
    for (int kk = 0; kk < 32; kk++) {
      float4 av = *(const float4*)&As[kk][ty * 4];
      float a[4] = {av.x, av.y, av.z, av.w};
      float bb[4];
      *(float2*)&bb[0] = *(const float2*)&Bs[kk][tx * 4];
      *(float2*)&bb[2] = *(const float2*)&Bs[kk][tx * 4 + 2];
#pragma unroll
      for (int i = 0; i < 4; i++)
#pragma unroll
        for (int j = 0; j < 4; j++) acc[i][j] += a[i] * bb[j];
    }
    __syncthreads();
  }
#pragma unroll
  for (int i = 0; i < 4; i++) {
    float m = mu[c0 + ty * 4 + i];
    float4 v = make_float4(acc[i][0] + m, acc[i][1] + m, acc[i][2] + m, acc[i][3] + m);
    *(float4*)&dst[(size_t)(c0 + ty * 4 + i) * NP + y0 + tx * 4] = v;
  }
}

// ---------------------------------------------------------------------------
extern "C" void kernel_launch(void* const* d_in, const int* in_sizes, int n_in,
                              void* d_out, int out_size, void* d_ws, size_t ws_size,
                              hipStream_t stream) {
  (void)in_sizes; (void)n_in; (void)out_size; (void)ws_size;
  const float* content = (const float*)d_in[0];
  const float* style = (const float*)d_in[1];
  float* out = (float*)d_out;

  // workspace carve-up (256B aligned)
  char* w = (char*)d_ws;
  auto alloc = [&](size_t bytes) -> void* {
    void* p = (void*)w;
    w += (bytes + 255) & ~(size_t)255;
    return p;
  };
  float* mean = (float*)alloc(2 * NB * NC * sizeof(float));
  double* pcov = (double*)alloc((size_t)KSPLIT * NM * NC * NC * sizeof(double));  // 32MB
  double* cov = (double*)alloc((size_t)NM * NC * NC * sizeof(double));
  float* Y0 = (float*)alloc((size_t)NM * NC * NC * sizeof(float));   // fp32 NS state
  float* Z0 = (float*)alloc((size_t)NM * NC * NC * sizeof(float));
  float* Y1 = (float*)alloc((size_t)NM * NC * NC * sizeof(float));
  float* Z1 = (float*)alloc((size_t)NM * NC * NC * sizeof(float));
  float* T = (float*)alloc((size_t)NM * NC * NC * sizeof(float));
  double* scaleArr = (double*)alloc(NM * sizeof(double));
  double* rowsum = (double*)alloc((size_t)NM * NC * sizeof(double));  // 16KB Gershgorin
  _Float16* Mh = (_Float16*)alloc((size_t)NM * NC * NC * sizeof(_Float16));  // 1MB
  _Float16* Ml = (_Float16*)alloc((size_t)NM * NC * NC * sizeof(_Float16));  // 1MB
  float* sqr_s = (float*)alloc((size_t)NB * NC * NC * sizeof(float));
  float* nswT = (float*)alloc((size_t)NB * NP * NC * sizeof(float));  // [p][c]
  float* ssqp = (float*)alloc((size_t)4 * NB * NP * sizeof(float));   // 4 partial slots
  float* rk = (float*)alloc((size_t)NB * NP * sizeof(float));
  unsigned long long* packed =
      (unsigned long long*)alloc((size_t)NB * NP * sizeof(unsigned long long));  // 128KB
  float* Dbuf = (float*)alloc((size_t)NP * NP * sizeof(float));  // 64MB, multi-overlaid:
  float* reass = Dbuf + (size_t)NB * NP * NC;          // [16MB, 32MB), used after score loop
  // raw fp16 split overlays Dbuf[0,32MB) — dead before dmat first writes Dbuf
  _Float16* Czh = (_Float16*)Dbuf;                       // 16MB: NM*NC*NP fp16 [k][p]
  _Float16* Czl = Czh + (size_t)NM * NC * NP;            // 16MB
  // transposed raw split overlays Dbuf[32MB,64MB) — also dead before dmat
  _Float16* CzhT = Czh + (size_t)2 * NM * NC * NP;       // 16MB: [p][k]
  _Float16* CzlT = CzhT + (size_t)NM * NC * NP;          // 16MB
  // whitened fp16 split arrays overlay pcov (dead after cov_reduce): 4 x 8MB
  _Float16* AhiT = (_Float16*)pcov;
  _Float16* AloT = AhiT + (size_t)NB * NP * NC;
  _Float16* BhiT = AloT + (size_t)NB * NP * NC;
  _Float16* BloT = BhiT + (size_t)NB * NP * NC;

  // 1-2: fused mean + raw split, then MFMA syrk cov
  meansplit_kernel<<<2 * NB * NC, 256, 0, stream>>>(content, style, mean, Czh, Czl);
  cov_mfma_kernel<<<dim3(10, KSPLIT, NM), 256, 0, stream>>>(Czh, Czl, pcov);
  cov_reduce_kernel<<<NM * NC * NC / 256, 256, 0, stream>>>(pcov, cov);

  // 2c: transpose raw split to [p][k] for the MFMA whiten A-operand
  transpose_kernel<<<dim3(NP / 64, NC / 64, NM), 256, 0, stream>>>(Czh, Czl, CzhT, CzlT);

  // 3-4: Newton-Schulz inverse/forward sqrt (fp32, Gershgorin-scaled,
  //      symmetric upper-tri tiles only)
  bound_rowsum_kernel<<<dim3(NC / 4, NM), 256, 0, stream>>>(cov, rowsum);
  bound_init2_kernel<<<dim3(NC * NC / 2048, NM), 256, 0, stream>>>(cov, rowsum,
                                                                   Y0, Z0, scaleArr);
  float *Ya = Y0, *Za = Z0, *Yb = Y1, *Zb = Z1;
  for (int it = 0; it < NS_ITERS; it++) {
    ns_t_kernel<<<dim3(NTILE8, 1, NM), 256, 0, stream>>>(Za, Ya, T);
    ns_upd_kernel<<<dim3(NTILE8, 1, NM * 2), 256, 0, stream>>>(Ya, Za, T, Yb, Zb);
    float* tmp;
    tmp = Ya; Ya = Yb; Yb = tmp;
    tmp = Za; Za = Zb; Zb = tmp;
  }
  finalize_kernel<<<dim3(NM * NC * NC / 256, 2), 256, 0, stream>>>(Ya, Za, scaleArr,
                                                                   Mh, Ml, sqr_s);

  // 6: MFMA whiten both features with fused fp16-split epilogue + style ssq
  whiten_mfma_kernel<<<dim3(NP / 128, NC / 128, NM), 256, 0, stream>>>(
      CzhT, CzlT, Mh, Ml, BhiT, BloT, AhiT, AloT, nswT, ssqp);

  // 7: knorm box from ssq partials
  rknorm_kernel<<<NB * NP / 256, 256, 0, stream>>>(ssqp, rk);

  // 8-9: zero packed argmax keys, then per batch: D = A B^T (MFMA fp16
  //      3-term), score with fused atomicMax argmax
  hipMemsetAsync(packed, 0, (size_t)NB * NP * sizeof(unsigned long long), stream);
  for (int b = 0; b < NB; b++) {
    dmat_kernel<<<dim3(NP / 128, NP / 128), 256, 0, stream>>>(AhiT, AloT, BhiT, BloT, Dbuf, b);
    score_kernel<<<dim3(NP / 256, NSLAB), 256, 0, stream>>>(Dbuf, rk, packed, b);
  }

  // 11: reassembly (gather form) straight from nswT, unpacking argmax keys
  reassemble_kernel<<<NB * NP, 256, 0, stream>>>(nswT, packed, reass);

  // 12: coloring straight into d_out (style_strength == 1.0)
  coloring_kernel<<<dim3(NC / 64, NP / 64, NB), 256, 0, stream>>>(sqr_s, reass, mean, out);
}